// Round 1
// baseline (335.966 us; speedup 1.0000x reference)
//
#include <hip/hip_runtime.h>
#include <hip/hip_bf16.h>

typedef __attribute__((ext_vector_type(8))) short short8;
typedef __attribute__((ext_vector_type(4))) float f32x4;
typedef __attribute__((ext_vector_type(4))) int int4v;

#define DI __device__ __forceinline__

constexpr int Bq = 4, Cc = 512, Ss = 8192, Ee = 256;

DI unsigned short f2bf(float f) {
    unsigned int u = __float_as_uint(f);
    unsigned int r = u + 0x7fffu + ((u >> 16) & 1u);
    return (unsigned short)(r >> 16);
}

union U16x8 { int4v v; unsigned short u[8]; };

// ---------- convert weights to bf16: Wqkv [768][512], Wo [512][256] ----------
__global__ __launch_bounds__(256) void kconv_w(
    const float* __restrict__ Wq, const float* __restrict__ Wk, const float* __restrict__ Wv,
    const float* __restrict__ Wo, unsigned short* __restrict__ Wqkv_b, unsigned short* __restrict__ Wo_b)
{
    int i = blockIdx.x * 256 + threadIdx.x;
    if (i < 768 * 512) {
        int m = i >> 9, c = i & 511;
        const float* src = (m < 256) ? Wq : ((m < 512) ? Wk : Wv);
        Wqkv_b[i] = f2bf(src[(m & 255) * 512 + c]);
    }
    if (i < 512 * 256) Wo_b[i] = f2bf(Wo[i]);
}

// ---------- transpose x1[b] (C,S) f32 -> xT (S,C) bf16 ----------
__global__ __launch_bounds__(256) void ktr_x(const float* __restrict__ x1b, unsigned short* __restrict__ xT)
{
    __shared__ unsigned short tile[64][72];
    int t = threadIdx.x;
    int bs = blockIdx.x & 127, bc = blockIdx.x >> 7;
    int s0 = bs * 64, c0 = bc * 64;
    int cl = t >> 4, sl = (t & 15) * 4;
    for (int it = 0; it < 4; ++it) {
        int c = cl + it * 16;
        float4 vv = *(const float4*)(x1b + (long)(c0 + c) * Ss + s0 + sl);
        tile[c][sl + 0] = f2bf(vv.x);
        tile[c][sl + 1] = f2bf(vv.y);
        tile[c][sl + 2] = f2bf(vv.z);
        tile[c][sl + 3] = f2bf(vv.w);
    }
    __syncthreads();
    int s_loc = t >> 2, cseg = (t & 3) * 16;
    for (int half = 0; half < 2; ++half) {
        U16x8 u;
        for (int j = 0; j < 8; ++j) u.u[j] = tile[cseg + half * 8 + j][s_loc];
        *(int4v*)(xT + (long)(s0 + s_loc) * Cc + c0 + cseg + half * 8) = u.v;
    }
}

// ---------- QKV GEMM (per batch): q,k -> OutT[s][e] (qT,kT), v -> Out[e][s] ----------
// Universal form: A [M][K] row-major, Bt [N][K] row-major, K=512, tile 128x128, BK=64.
__global__ __launch_bounds__(256) void kqkv(
    const unsigned short* __restrict__ xT, const unsigned short* __restrict__ Wqkv,
    const float* __restrict__ bq, const float* __restrict__ bk, const float* __restrict__ bv,
    unsigned short* __restrict__ qT, unsigned short* __restrict__ kT, unsigned short* __restrict__ vO,
    int b)
{
    __shared__ int4v As[1024], Bs[1024];   // 128 rows x 8 segs (16B) each
    int wg = blockIdx.x;
    int type = wg >> 7, id = wg & 127;     // 0=q 1=k 2=v
    const unsigned short *A, *Bt; unsigned short* Op;
    long opitch; const float* bias; bool biasRow;
    if (type < 2) {
        int mt = id >> 1, nt = id & 1;
        A  = xT + (long)(mt * 128) * 512;
        Bt = Wqkv + (long)(type * 256 + nt * 128) * 512;
        Op = (type ? kT : qT) + (long)b * Ss * Ee + (long)(mt * 128) * Ee + nt * 128;
        opitch = Ee;
        bias = (type ? bk : bq) + nt * 128;
        biasRow = false;
    } else {
        int mt = id >> 6, nt = id & 63;
        A  = Wqkv + (long)(512 + mt * 128) * 512;
        Bt = xT + (long)(nt * 128) * 512;
        Op = vO + (long)b * Ee * Ss + (long)(mt * 128) * Ss + nt * 128;
        opitch = Ss;
        bias = bv + mt * 128;
        biasRow = true;
    }
    int t = threadIdx.x, lane = t & 63, wv = t >> 6;
    int wr = (wv >> 1) * 64, wc = (wv & 1) * 64;
    f32x4 acc[4][4] = {};
    for (int kk = 0; kk < 8; ++kk) {
        __syncthreads();
        for (int i = 0; i < 4; ++i) {
            int seg = t + 256 * i;
            int row = seg >> 3, cs = seg & 7;
            int4v va = *(const int4v*)(A  + (long)row * 512 + kk * 64 + cs * 8);
            int4v vb = *(const int4v*)(Bt + (long)row * 512 + kk * 64 + cs * 8);
            As[row * 8 + (cs ^ (row & 7))] = va;
            Bs[row * 8 + (cs ^ (row & 7))] = vb;
        }
        __syncthreads();
        for (int ks = 0; ks < 2; ++ks) {
            int csk = ks * 4 + (lane >> 4);
            short8 af[4], bfr[4];
            #pragma unroll
            for (int mi = 0; mi < 4; ++mi) {
                int m = wr + mi * 16 + (lane & 15);
                af[mi] = *(const short8*)&As[m * 8 + (csk ^ (m & 7))];
            }
            #pragma unroll
            for (int ni = 0; ni < 4; ++ni) {
                int nn = wc + ni * 16 + (lane & 15);
                bfr[ni] = *(const short8*)&Bs[nn * 8 + (csk ^ (nn & 7))];
            }
            #pragma unroll
            for (int mi = 0; mi < 4; ++mi)
                #pragma unroll
                for (int ni = 0; ni < 4; ++ni)
                    acc[mi][ni] = __builtin_amdgcn_mfma_f32_16x16x32_bf16(af[mi], bfr[ni], acc[mi][ni], 0, 0, 0);
        }
    }
    for (int mi = 0; mi < 4; ++mi)
        for (int ni = 0; ni < 4; ++ni) {
            int mrow = wr + mi * 16 + ((lane >> 4) * 4);
            int ncol = wc + ni * 16 + (lane & 15);
            for (int r = 0; r < 4; ++r) {
                float bval = biasRow ? bias[mrow + r] : bias[ncol];
                Op[(long)(mrow + r) * opitch + ncol] = f2bf(acc[mi][ni][r] + bval);
            }
        }
}

// ---------- fused attention + gelu + output projection ----------
// Grid: b(4) x n(32) x qtile(4); 256 thr (4 waves); wave owns 16 q-rows.
__global__ __launch_bounds__(256) void kattn(
    const unsigned short* __restrict__ qT, const unsigned short* __restrict__ kT,
    const unsigned short* __restrict__ v,  const unsigned short* __restrict__ Wo_b,
    const float* __restrict__ mask, const float* __restrict__ bo,
    float* __restrict__ y)
{
    __shared__ int4v Aq[2048];          // 32KB: q tile [64q][256e]; reused as h tile
    __shared__ int4v Bts[2048];         // 32KB: k-chunk [64w][256e] / v-chunk [256e][64w] / Wo-chunk [64o][256e]
    __shared__ __align__(16) unsigned short Pl[4096];  // 8KB: P [64q][64w]
    __shared__ float fmaskL[512];
    __shared__ float lmaskL[512];

    int t = threadIdx.x, lane = t & 63, wv = t >> 6;
    int wg = blockIdx.x;
    int qt = wg & 3, n = (wg >> 2) & 31, b = wg >> 7;
    int sq0 = n * 256 + qt * 64;

    for (int i = t; i < 512; i += 256) {
        int sw = n * 256 - 128 + i;
        float f = 0.f;
        if (i != 511 && sw >= 0 && sw < Ss) f = mask[(long)b * Ss + sw];
        fmaskL[i] = f;
        lmaskL[i] = logf(f + 1e-6f);
    }
    {
        const unsigned short* src = qT + ((long)b * Ss + sq0) * Ee;
        for (int i = 0; i < 8; ++i) {
            int seg = t + 256 * i;
            int row = seg >> 5, cs = seg & 31;
            Aq[row * 32 + (cs ^ (row & 7))] = *(const int4v*)(src + (long)row * Ee + cs * 8);
        }
    }
    __syncthreads();

    float mrun[4], lrun[4];
    for (int r = 0; r < 4; ++r) { mrun[r] = -3.4e38f; lrun[r] = 0.f; }
    f32x4 oacc[16] = {};
    int qr0 = wv * 16;

    for (int ch = 0; ch < 8; ++ch) {
        int w0 = ch * 64;
        int swbase = n * 256 - 128 + w0;
        // stage k-chunk (rows = w-local, zero OOB)
        for (int i = 0; i < 8; ++i) {
            int seg = t + 256 * i;
            int row = seg >> 5, cs = seg & 31;
            int sw = swbase + row;
            int4v val = {0, 0, 0, 0};
            if (sw >= 0 && sw < Ss)
                val = *(const int4v*)(kT + ((long)b * Ss + sw) * Ee + cs * 8);
            Bts[row * 32 + (cs ^ (row & 7))] = val;
        }
        __syncthreads();
        // energy = q . k
        f32x4 eacc[4] = {};
        for (int ks = 0; ks < 8; ++ks) {
            int csk = ks * 4 + (lane >> 4);
            int mrow = qr0 + (lane & 15);
            short8 a = *(const short8*)&Aq[mrow * 32 + (csk ^ (mrow & 7))];
            #pragma unroll
            for (int ni = 0; ni < 4; ++ni) {
                int nrow = ni * 16 + (lane & 15);
                short8 bb = *(const short8*)&Bts[nrow * 32 + (csk ^ (nrow & 7))];
                eacc[ni] = __builtin_amdgcn_mfma_f32_16x16x32_bf16(a, bb, eacc[ni], 0, 0, 0);
            }
        }
        // online softmax (fp32)
        float ev[4][4], rmax[4];
        for (int r = 0; r < 4; ++r) rmax[r] = -3.4e38f;
        for (int ni = 0; ni < 4; ++ni) {
            float lm = lmaskL[w0 + ni * 16 + (lane & 15)];
            for (int r = 0; r < 4; ++r) {
                float e = eacc[ni][r] * 0.0625f + lm;
                ev[ni][r] = e;
                rmax[r] = fmaxf(rmax[r], e);
            }
        }
        for (int mm = 1; mm < 16; mm <<= 1)
            for (int r = 0; r < 4; ++r)
                rmax[r] = fmaxf(rmax[r], __shfl_xor(rmax[r], mm));
        float scl[4], rsum[4];
        for (int r = 0; r < 4; ++r) {
            float mn = fmaxf(mrun[r], rmax[r]);
            scl[r] = expf(mrun[r] - mn);
            mrun[r] = mn;
            rsum[r] = 0.f;
        }
        for (int ni = 0; ni < 4; ++ni) {
            int wl = ni * 16 + (lane & 15);
            float fm = fmaskL[w0 + wl];
            for (int r = 0; r < 4; ++r) {
                float p = expf(ev[ni][r] - mrun[r]);
                rsum[r] += p;
                int row = qr0 + (lane >> 4) * 4 + r;
                int byt = row * 128 + (((wl >> 3) ^ (row & 7)) << 4) + (wl & 7) * 2;
                *(unsigned short*)((char*)Pl + byt) = f2bf(p * fm);
            }
        }
        for (int mm = 1; mm < 16; mm <<= 1)
            for (int r = 0; r < 4; ++r)
                rsum[r] += __shfl_xor(rsum[r], mm);
        for (int r = 0; r < 4; ++r)
            lrun[r] = lrun[r] * scl[r] + rsum[r];
        #pragma unroll
        for (int ni = 0; ni < 16; ++ni)
            for (int r = 0; r < 4; ++r)
                oacc[ni][r] *= scl[r];
        __syncthreads();
        // stage v-chunk (rows = e, cols = w-local, zero OOB; 8-elem segs fully in/out)
        for (int i = 0; i < 8; ++i) {
            int seg = t + 256 * i;
            int row = seg >> 3, cs = seg & 7;
            int sw = swbase + cs * 8;
            int4v val = {0, 0, 0, 0};
            if (sw >= 0 && sw < Ss)
                val = *(const int4v*)(v + ((long)b * Ee + row) * Ss + sw);
            Bts[row * 8 + (cs ^ (row & 7))] = val;
        }
        __syncthreads();
        // PV: oacc[q][e] += P . v
        for (int ks = 0; ks < 2; ++ks) {
            int csk = ks * 4 + (lane >> 4);
            int mrow = qr0 + (lane & 15);
            short8 a = *(const short8*)((char*)Pl + mrow * 128 + ((csk ^ (mrow & 7)) << 4));
            #pragma unroll
            for (int ni = 0; ni < 16; ++ni) {
                int nrow = ni * 16 + (lane & 15);
                short8 bb = *(const short8*)&Bts[nrow * 8 + (csk ^ (nrow & 7))];
                oacc[ni] = __builtin_amdgcn_mfma_f32_16x16x32_bf16(a, bb, oacc[ni], 0, 0, 0);
            }
        }
        __syncthreads();
    }

    // finalize: /l, gelu(exact), write h tile into Aq region [64q][256e]
    float linv[4];
    for (int r = 0; r < 4; ++r) linv[r] = 1.f / lrun[r];
    for (int ni = 0; ni < 16; ++ni) {
        int e = ni * 16 + (lane & 15);
        for (int r = 0; r < 4; ++r) {
            float x = oacc[ni][r] * linv[r];
            float g = 0.5f * x * (1.f + erff(x * 0.70710678f));
            int row = qr0 + (lane >> 4) * 4 + r;
            int byt = row * 512 + (((e >> 3) ^ (row & 7)) << 4) + (e & 7) * 2;
            *(unsigned short*)((char*)Aq + byt) = f2bf(g);
        }
    }
    __syncthreads();

    // output projection: y[o][s] = Wo . h^T + bo, masked
    for (int oc = 0; oc < 8; ++oc) {
        for (int i = 0; i < 8; ++i) {
            int seg = t + 256 * i;
            int row = seg >> 5, cs = seg & 31;
            Bts[row * 32 + (cs ^ (row & 7))] = *(const int4v*)(Wo_b + (long)(oc * 64 + row) * Ee + cs * 8);
        }
        __syncthreads();
        f32x4 pacc[4] = {};
        for (int ks = 0; ks < 8; ++ks) {
            int csk = ks * 4 + (lane >> 4);
            int mrow = wv * 16 + (lane & 15);
            short8 a = *(const short8*)&Bts[mrow * 32 + (csk ^ (mrow & 7))];
            #pragma unroll
            for (int ni = 0; ni < 4; ++ni) {
                int nrow = ni * 16 + (lane & 15);
                short8 bb = *(const short8*)((char*)Aq + nrow * 512 + ((csk ^ (nrow & 7)) << 4));
                pacc[ni] = __builtin_amdgcn_mfma_f32_16x16x32_bf16(a, bb, pacc[ni], 0, 0, 0);
            }
        }
        for (int ni = 0; ni < 4; ++ni) {
            int qcol = ni * 16 + (lane & 15);
            int s = sq0 + qcol;
            float mk = mask[(long)b * Ss + s];
            for (int r = 0; r < 4; ++r) {
                int o = oc * 64 + wv * 16 + (lane >> 4) * 4 + r;
                y[((long)b * Cc + o) * Ss + s] = (pacc[ni][r] + bo[o]) * mk;
            }
        }
        __syncthreads();
    }
}

extern "C" void kernel_launch(void* const* d_in, const int* in_sizes, int n_in,
                              void* d_out, int out_size, void* d_ws, size_t ws_size,
                              hipStream_t stream)
{
    const float* x1   = (const float*)d_in[0];
    const float* mask = (const float*)d_in[1];
    const float* Wq   = (const float*)d_in[2];
    const float* bq   = (const float*)d_in[3];
    const float* Wk   = (const float*)d_in[4];
    const float* bk   = (const float*)d_in[5];
    const float* Wv   = (const float*)d_in[6];
    const float* bv   = (const float*)d_in[7];
    const float* Wo   = (const float*)d_in[8];
    const float* bo   = (const float*)d_in[9];
    float* y = (float*)d_out;

    // ws layout (bf16 buffers), total 59,768,832 B
    if (ws_size < 59768832u) return;
    char* w = (char*)d_ws;
    unsigned short* Wqkv_b = (unsigned short*)(w);               // 768*512*2   = 786432
    unsigned short* Wo_b   = (unsigned short*)(w + 786432);      // 512*256*2   = 262144
    unsigned short* xT     = (unsigned short*)(w + 1048576);     // 8192*512*2  = 8388608 (per-batch slab)
    unsigned short* qT     = (unsigned short*)(w + 9437184);     // 4*8192*256*2 = 16777216
    unsigned short* kT     = (unsigned short*)(w + 26214400);    // 16777216
    unsigned short* v      = (unsigned short*)(w + 42991616);    // 16777216

    kconv_w<<<1536, 256, 0, stream>>>(Wq, Wk, Wv, Wo, Wqkv_b, Wo_b);
    for (int b = 0; b < 4; ++b) {
        ktr_x<<<1024, 256, 0, stream>>>(x1 + (long)b * Cc * Ss, xT);
        kqkv<<<384, 256, 0, stream>>>(xT, Wqkv_b, bq, bk, bv, qT, kT, v, b);
    }
    kattn<<<512, 256, 0, stream>>>(qT, kT, v, Wo_b, mask, bo, y);
}

// Round 2
// 203.140 us; speedup vs baseline: 1.6539x; 1.6539x over previous
//
#include <hip/hip_runtime.h>
#include <hip/hip_bf16.h>

typedef __attribute__((ext_vector_type(8))) short short8;
typedef __attribute__((ext_vector_type(4))) float f32x4;
typedef __attribute__((ext_vector_type(4))) int int4v;

#define DI __device__ __forceinline__

constexpr int Bq = 4, Cc = 512, Ss = 8192, Ee = 256;
constexpr int SP = 8448;   // padded s extent (128 + 8192 + 128)

DI unsigned short f2bf(float f) {
    unsigned int u = __float_as_uint(f);
    unsigned int r = u + 0x7fffu + ((u >> 16) & 1u);
    return (unsigned short)(r >> 16);
}

union U16x8 { int4v v; unsigned short u[8]; };

DI void gll16(const void* g, void* l) {
    __builtin_amdgcn_global_load_lds(
        (const __attribute__((address_space(1))) unsigned int*)g,
        (__attribute__((address_space(3))) unsigned int*)l, 16, 0, 0);
}

// ---------- convert weights to bf16: Wqkv [768][512], Wo [512][256] ----------
__global__ __launch_bounds__(256) void kconv_w(
    const float* __restrict__ Wq, const float* __restrict__ Wk, const float* __restrict__ Wv,
    const float* __restrict__ Wo, unsigned short* __restrict__ Wqkv_b, unsigned short* __restrict__ Wo_b)
{
    int i = blockIdx.x * 256 + threadIdx.x;
    if (i < 768 * 512) {
        int m = i >> 9, c = i & 511;
        const float* src = (m < 256) ? Wq : ((m < 512) ? Wk : Wv);
        Wqkv_b[i] = f2bf(src[(m & 255) * 512 + c]);
    }
    if (i < 512 * 256) Wo_b[i] = f2bf(Wo[i]);
}

// ---------- zero pads of kTp (rows) and vp (cols) ----------
__global__ __launch_bounds__(256) void kzero(unsigned short* __restrict__ kTp, unsigned short* __restrict__ vp)
{
    int i = blockIdx.x * 256 + threadIdx.x;    // 65536 16B segs total
    int4v z = {0, 0, 0, 0};
    if (i < 32768) {           // k pads: 4 batches x 2 sides x 128 rows x 32 segs
        int b = i >> 13, r = i & 8191;
        int side = r >> 12, off = r & 4095;
        *(int4v*)(kTp + (long)b * SP * 256 + (long)(side ? 8320 : 0) * 256 + off * 8) = z;
    } else {                   // v pads: 4 batches x 256 rows x 2 sides x 16 segs
        int j = i - 32768;
        int b = j >> 13, r = j & 8191;
        int row = r >> 5, side = (r >> 4) & 1, sc = r & 15;
        *(int4v*)(vp + ((long)b * 256 + row) * SP + side * 8320 + sc * 8) = z;
    }
}

// ---------- transpose x1[b] (C,S) f32 -> xT (S,C) bf16 ----------
__global__ __launch_bounds__(256) void ktr_x(const float* __restrict__ x1b, unsigned short* __restrict__ xT)
{
    __shared__ unsigned short tile[64][72];
    int t = threadIdx.x;
    int bs = blockIdx.x & 127, bc = blockIdx.x >> 7;
    int s0 = bs * 64, c0 = bc * 64;
    int cl = t >> 4, sl = (t & 15) * 4;
    for (int it = 0; it < 4; ++it) {
        int c = cl + it * 16;
        float4 vv = *(const float4*)(x1b + (long)(c0 + c) * Ss + s0 + sl);
        tile[c][sl + 0] = f2bf(vv.x);
        tile[c][sl + 1] = f2bf(vv.y);
        tile[c][sl + 2] = f2bf(vv.z);
        tile[c][sl + 3] = f2bf(vv.w);
    }
    __syncthreads();
    int s_loc = t >> 2, cseg = (t & 3) * 16;
    for (int half = 0; half < 2; ++half) {
        U16x8 u;
        for (int j = 0; j < 8; ++j) u.u[j] = tile[cseg + half * 8 + j][s_loc];
        *(int4v*)(xT + (long)(s0 + s_loc) * Cc + c0 + cseg + half * 8) = u.v;
    }
}

// ---------- QKV GEMM (per batch): q,k -> [s][e] (qT unpadded, kTp padded rows), v -> [e][s] padded cols ----------
__global__ __launch_bounds__(256) void kqkv(
    const unsigned short* __restrict__ xT, const unsigned short* __restrict__ Wqkv,
    const float* __restrict__ bq, const float* __restrict__ bk, const float* __restrict__ bv,
    unsigned short* __restrict__ qT, unsigned short* __restrict__ kTp, unsigned short* __restrict__ vp,
    int b)
{
    __shared__ int4v As[1024], Bs[1024];
    int wg = blockIdx.x;
    int type = wg >> 7, id = wg & 127;     // 0=q 1=k 2=v
    const unsigned short *A, *Bt; unsigned short* Op;
    long opitch; const float* bias; bool biasRow;
    if (type < 2) {
        int mt = id >> 1, nt = id & 1;
        A  = xT + (long)(mt * 128) * 512;
        Bt = Wqkv + (long)(type * 256 + nt * 128) * 512;
        if (type == 0)
            Op = qT + (long)b * Ss * Ee + (long)(mt * 128) * Ee + nt * 128;
        else
            Op = kTp + (long)b * SP * Ee + (long)(128 + mt * 128) * Ee + nt * 128;
        opitch = Ee;
        bias = (type ? bk : bq) + nt * 128;
        biasRow = false;
    } else {
        int mt = id >> 6, nt = id & 63;
        A  = Wqkv + (long)(512 + mt * 128) * 512;
        Bt = xT + (long)(nt * 128) * 512;
        Op = vp + (long)b * Ee * SP + (long)(mt * 128) * SP + 128 + nt * 128;
        opitch = SP;
        bias = bv + mt * 128;
        biasRow = true;
    }
    int t = threadIdx.x, lane = t & 63, wv = t >> 6;
    int wr = (wv >> 1) * 64, wc = (wv & 1) * 64;
    f32x4 acc[4][4] = {};
    for (int kk = 0; kk < 8; ++kk) {
        __syncthreads();
        for (int i = 0; i < 4; ++i) {
            int seg = t + 256 * i;
            int row = seg >> 3, cs = seg & 7;
            int4v va = *(const int4v*)(A  + (long)row * 512 + kk * 64 + cs * 8);
            int4v vb = *(const int4v*)(Bt + (long)row * 512 + kk * 64 + cs * 8);
            As[row * 8 + (cs ^ (row & 7))] = va;
            Bs[row * 8 + (cs ^ (row & 7))] = vb;
        }
        __syncthreads();
        for (int ks = 0; ks < 2; ++ks) {
            int csk = ks * 4 + (lane >> 4);
            short8 af[4], bfr[4];
            #pragma unroll
            for (int mi = 0; mi < 4; ++mi) {
                int m = wr + mi * 16 + (lane & 15);
                af[mi] = *(const short8*)&As[m * 8 + (csk ^ (m & 7))];
            }
            #pragma unroll
            for (int ni = 0; ni < 4; ++ni) {
                int nn = wc + ni * 16 + (lane & 15);
                bfr[ni] = *(const short8*)&Bs[nn * 8 + (csk ^ (nn & 7))];
            }
            #pragma unroll
            for (int mi = 0; mi < 4; ++mi)
                #pragma unroll
                for (int ni = 0; ni < 4; ++ni)
                    acc[mi][ni] = __builtin_amdgcn_mfma_f32_16x16x32_bf16(af[mi], bfr[ni], acc[mi][ni], 0, 0, 0);
        }
    }
    for (int mi = 0; mi < 4; ++mi)
        for (int ni = 0; ni < 4; ++ni) {
            int mrow = wr + mi * 16 + ((lane >> 4) * 4);
            int ncol = wc + ni * 16 + (lane & 15);
            for (int r = 0; r < 4; ++r) {
                float bval = biasRow ? bias[mrow + r] : bias[ncol];
                Op[(long)(mrow + r) * opitch + ncol] = f2bf(acc[mi][ni][r] + bval);
            }
        }
}

// ---------- fused attention + gelu + output projection (pipelined) ----------
// grid 512: (b,n,qt) via XCD swizzle; 4 waves; wave owns 16 q-rows; chunk = 32 keys.
__global__ __launch_bounds__(256) void kattn(
    const unsigned short* __restrict__ qT, const unsigned short* __restrict__ kTp,
    const unsigned short* __restrict__ vp,  const unsigned short* __restrict__ Wo_b,
    const float* __restrict__ mask, const float* __restrict__ bo,
    float* __restrict__ y)
{
    // SH layout (int4v units):
    // [0,1024) K0 | [1024,2048) K1 | [2048,3072) V0 | [3072,4096) V1
    // [4096,4352) P | [4352,4480) fmask | [4480,4608) lmask | [4608,4736) bo
    __shared__ int4v SH[4736];
    unsigned short* Plb = (unsigned short*)(SH + 4096);
    float* fmaskL = (float*)(SH + 4352);
    float* lmaskL = (float*)(SH + 4480);
    float* boL    = (float*)(SH + 4608);

    int t = threadIdx.x, lane = t & 63, wv = t >> 6;
    int phys = blockIdx.x;
    int wg = (phys & 7) * 64 + (phys >> 3);      // XCD-bijective swizzle (512 % 8 == 0)
    int qt = wg & 3, n = (wg >> 2) & 31, b = wg >> 7;
    int sq0 = n * 256 + qt * 64;
    int qr0 = wv * 16;

    // --- issue q stage (64 rows x 512B) into SH[0,2048), pre-swizzled source
    {
        int rb = wv * 2 + (lane >> 5);           // row base within 8-row stripe
        int segq = (lane & 31) ^ rb;
        const unsigned short* src = qT + ((long)b * Ss + sq0 + rb) * Ee + segq * 8;
        char* ldsb = (char*)SH + (wv * 2) * 512;
        #pragma unroll
        for (int i = 0; i < 8; ++i)
            gll16(src + (long)(i * 8) * Ee, ldsb + i * 8 * 512);
    }
    // --- masks + bias to LDS (normal loads)
    for (int i = t; i < 512; i += 256) {
        int sw = n * 256 - 128 + i;
        float f = 0.f;
        if (i != 511 && sw >= 0 && sw < Ss) f = mask[(long)b * Ss + sw];
        fmaskL[i] = f;
        lmaskL[i] = __logf(f + 1e-6f);
    }
    if (t < 128) ((float4*)boL)[t] = ((const float4*)bo)[t];

    asm volatile("s_waitcnt vmcnt(0) lgkmcnt(0)" ::: "memory");
    __builtin_amdgcn_s_barrier();

    // --- q fragments to registers
    short8 qreg[8];
    {
        int mrow = qr0 + (lane & 15);
        #pragma unroll
        for (int ks = 0; ks < 8; ++ks) {
            int csk = ks * 4 + (lane >> 4);
            qreg[ks] = *(const short8*)&SH[mrow * 32 + (csk ^ (mrow & 7))];
        }
    }
    asm volatile("s_waitcnt lgkmcnt(0)" ::: "memory");
    __builtin_amdgcn_s_barrier();

    // --- per-thread staging constants (pre-swizzled global sources)
    // K: per instr rows i*8 + rbK (rbK = wv*2 + (lane>>5)); seg' = (lane&31)^rbK
    int rbK = wv * 2 + (lane >> 5);
    int segK = (lane & 31) ^ rbK;
    const unsigned short* ksrc0 = kTp + ((long)b * SP + n * 256 + rbK) * Ee + segK * 8;
    // V: per instr rows i*64 + rbV (rbV = wv*16 + (lane>>2)); seg' = (lane&3)^((lane>>3)&3)
    int rbV = wv * 16 + (lane >> 2);
    int segV = (lane & 3) ^ ((lane >> 3) & 3);
    const unsigned short* vsrc0 = vp + ((long)b * Ee + rbV) * SP + n * 256 + segV * 8;

    #define ISSUE_KV(CH, BUF)                                                        \
        {                                                                            \
            int w0_ = (CH) * 32;                                                     \
            char* kl = (char*)SH + (BUF) * 16384 + (wv * 2) * 512;                   \
            char* vl = (char*)SH + 32768 + (BUF) * 16384 + (wv * 16) * 64;           \
            _Pragma("unroll")                                                        \
            for (int i = 0; i < 4; ++i)                                              \
                gll16(ksrc0 + ((long)w0_ + i * 8) * Ee, kl + i * 8 * 512);           \
            _Pragma("unroll")                                                        \
            for (int i = 0; i < 4; ++i)                                              \
                gll16(vsrc0 + (long)i * 64 * SP + w0_, vl + i * 64 * 64);            \
        }

    ISSUE_KV(0, 0)
    ISSUE_KV(1, 1)
    asm volatile("s_waitcnt vmcnt(8)" ::: "memory");
    __builtin_amdgcn_s_barrier();

    float mrun[4], lrun[4];
    #pragma unroll
    for (int r = 0; r < 4; ++r) { mrun[r] = -1e30f; lrun[r] = 0.f; }
    f32x4 oacc[16] = {};

    #pragma unroll 2
    for (int ch = 0; ch < 16; ++ch) {
        int cur = ch & 1;
        int w0 = ch * 32;
        const int4v* KB = SH + cur * 1024;
        const int4v* VB = SH + 2048 + cur * 1024;

        // energy [16q x 32w]
        f32x4 eacc[2] = {};
        #pragma unroll
        for (int ks = 0; ks < 8; ++ks) {
            int csk = ks * 4 + (lane >> 4);
            #pragma unroll
            for (int ni = 0; ni < 2; ++ni) {
                int nrow = ni * 16 + (lane & 15);
                short8 bb = *(const short8*)&KB[nrow * 32 + (csk ^ (nrow & 7))];
                eacc[ni] = __builtin_amdgcn_mfma_f32_16x16x32_bf16(qreg[ks], bb, eacc[ni], 0, 0, 0);
            }
        }
        // online softmax with defer-max
        float ev[2][4], rmax[4];
        #pragma unroll
        for (int r = 0; r < 4; ++r) rmax[r] = -1e30f;
        #pragma unroll
        for (int ni = 0; ni < 2; ++ni) {
            float lm = lmaskL[w0 + ni * 16 + (lane & 15)];
            #pragma unroll
            for (int r = 0; r < 4; ++r) {
                float e = eacc[ni][r] * 0.0625f + lm;
                ev[ni][r] = e;
                rmax[r] = fmaxf(rmax[r], e);
            }
        }
        #pragma unroll
        for (int mm = 1; mm < 16; mm <<= 1)
            #pragma unroll
            for (int r = 0; r < 4; ++r)
                rmax[r] = fmaxf(rmax[r], __shfl_xor(rmax[r], mm));
        int big = (rmax[0] > mrun[0] + 8.f) | (rmax[1] > mrun[1] + 8.f) |
                  (rmax[2] > mrun[2] + 8.f) | (rmax[3] > mrun[3] + 8.f);
        if (__any(big)) {
            #pragma unroll
            for (int r = 0; r < 4; ++r) {
                float mn = fmaxf(mrun[r], rmax[r]);
                float s = __expf(mrun[r] - mn);
                mrun[r] = mn;
                lrun[r] *= s;
                #pragma unroll
                for (int ni = 0; ni < 16; ++ni) oacc[ni][r] *= s;
            }
        }
        float rsum[4] = {0.f, 0.f, 0.f, 0.f};
        #pragma unroll
        for (int ni = 0; ni < 2; ++ni) {
            int wl = ni * 16 + (lane & 15);
            float fm = fmaskL[w0 + wl];
            #pragma unroll
            for (int r = 0; r < 4; ++r) {
                float p = __expf(ev[ni][r] - mrun[r]);
                rsum[r] += p;
                int row = qr0 + (lane >> 4) * 4 + r;
                *(unsigned short*)((char*)Plb + row * 64 + (((wl >> 3) ^ ((row >> 1) & 3)) << 4) + (wl & 7) * 2) = f2bf(p * fm);
            }
        }
        #pragma unroll
        for (int mm = 1; mm < 16; mm <<= 1)
            #pragma unroll
            for (int r = 0; r < 4; ++r)
                rsum[r] += __shfl_xor(rsum[r], mm);
        #pragma unroll
        for (int r = 0; r < 4; ++r) lrun[r] += rsum[r];

        // PV: oacc[q][e] += P . V
        {
            int csk = lane >> 4;
            int mrow = qr0 + (lane & 15);
            short8 a = *(const short8*)((char*)Plb + mrow * 64 + ((csk ^ ((mrow >> 1) & 3)) << 4));
            #pragma unroll
            for (int ni = 0; ni < 16; ++ni) {
                int nrow = ni * 16 + (lane & 15);
                short8 bb = *(const short8*)&VB[nrow * 4 + (csk ^ ((nrow >> 1) & 3))];
                oacc[ni] = __builtin_amdgcn_mfma_f32_16x16x32_bf16(a, bb, oacc[ni], 0, 0, 0);
            }
        }

        asm volatile("s_waitcnt lgkmcnt(0)" ::: "memory");
        __builtin_amdgcn_s_barrier();
        if (ch <= 13) {
            ISSUE_KV(ch + 2, cur)
            asm volatile("s_waitcnt vmcnt(8)" ::: "memory");
        } else {
            asm volatile("s_waitcnt vmcnt(0)" ::: "memory");
        }
        __builtin_amdgcn_s_barrier();
    }

    // --- finalize: /l, gelu, h -> LDS [64][256] bf16 at SH+2048
    {
        float linv[4];
        #pragma unroll
        for (int r = 0; r < 4; ++r) linv[r] = 1.f / lrun[r];
        char* H = (char*)(SH + 2048);
        #pragma unroll
        for (int ni = 0; ni < 16; ++ni) {
            int e = ni * 16 + (lane & 15);
            #pragma unroll
            for (int r = 0; r < 4; ++r) {
                float x = oacc[ni][r] * linv[r];
                float g = 0.5f * x * (1.f + erff(x * 0.70710678f));
                int row = qr0 + (lane >> 4) * 4 + r;
                *(unsigned short*)(H + row * 512 + (((e >> 3) ^ (row & 7)) << 4) + (e & 7) * 2) = f2bf(g);
            }
        }
    }
    asm volatile("s_waitcnt lgkmcnt(0)" ::: "memory");
    __builtin_amdgcn_s_barrier();

    // --- output projection: per oc (32 o-rows): y = Wo . h^T + bo
    {
        int mo = wv & 1, qp = wv >> 1;
        int rbW = wv * 2 + (lane >> 5);
        int segW = (lane & 31) ^ rbW;
        const unsigned short* wsrc0 = Wo_b + (long)(rbW) * Ee + segW * 8;
        char* wl = (char*)SH + (wv * 2) * 512;
        const int4v* H = SH + 2048;
        for (int oc = 0; oc < 16; ++oc) {
            #pragma unroll
            for (int i = 0; i < 4; ++i)
                gll16(wsrc0 + (long)(oc * 32 + i * 8) * Ee, wl + i * 8 * 512);
            asm volatile("s_waitcnt vmcnt(0)" ::: "memory");
            __builtin_amdgcn_s_barrier();
            f32x4 pacc[2] = {};
            #pragma unroll
            for (int ks = 0; ks < 8; ++ks) {
                int csk = ks * 4 + (lane >> 4);
                int mrow = mo * 16 + (lane & 15);
                short8 a = *(const short8*)&SH[mrow * 32 + (csk ^ (mrow & 7))];
                #pragma unroll
                for (int ni = 0; ni < 2; ++ni) {
                    int nrow = qp * 32 + ni * 16 + (lane & 15);
                    short8 bb = *(const short8*)&H[nrow * 32 + (csk ^ (nrow & 7))];
                    pacc[ni] = __builtin_amdgcn_mfma_f32_16x16x32_bf16(a, bb, pacc[ni], 0, 0, 0);
                }
            }
            #pragma unroll
            for (int ni = 0; ni < 2; ++ni) {
                int qcol = qp * 32 + ni * 16 + (lane & 15);
                int s = sq0 + qcol;
                float mk = fmaskL[128 + qt * 64 + qcol];
                #pragma unroll
                for (int r = 0; r < 4; ++r) {
                    int o = oc * 32 + mo * 16 + (lane >> 4) * 4 + r;
                    y[((long)b * Cc + o) * Ss + s] = (pacc[ni][r] + boL[o]) * mk;
                }
            }
            asm volatile("s_waitcnt lgkmcnt(0)" ::: "memory");
            __builtin_amdgcn_s_barrier();
        }
    }
}

extern "C" void kernel_launch(void* const* d_in, const int* in_sizes, int n_in,
                              void* d_out, int out_size, void* d_ws, size_t ws_size,
                              hipStream_t stream)
{
    const float* x1   = (const float*)d_in[0];
    const float* mask = (const float*)d_in[1];
    const float* Wq   = (const float*)d_in[2];
    const float* bq   = (const float*)d_in[3];
    const float* Wk   = (const float*)d_in[4];
    const float* bk   = (const float*)d_in[5];
    const float* Wv   = (const float*)d_in[6];
    const float* bv   = (const float*)d_in[7];
    const float* Wo   = (const float*)d_in[8];
    const float* bo   = (const float*)d_in[9];
    float* y = (float*)d_out;

    // ws layout (bf16):
    // Wqkv_b 786432 | Wo_b 262144 | xT 8388608 | qT 16777216 | kTp 17301504 | vp 17301504
    if (ws_size < 60817408u) return;
    char* w = (char*)d_ws;
    unsigned short* Wqkv_b = (unsigned short*)(w);
    unsigned short* Wo_b   = (unsigned short*)(w + 786432);
    unsigned short* xT     = (unsigned short*)(w + 1048576);
    unsigned short* qT     = (unsigned short*)(w + 9437184);
    unsigned short* kTp    = (unsigned short*)(w + 26214400);
    unsigned short* vp     = (unsigned short*)(w + 43515904);

    kconv_w<<<1536, 256, 0, stream>>>(Wq, Wk, Wv, Wo, Wqkv_b, Wo_b);
    kzero<<<256, 256, 0, stream>>>(kTp, vp);
    for (int b = 0; b < 4; ++b) {
        ktr_x<<<1024, 256, 0, stream>>>(x1 + (long)b * Cc * Ss, xT);
        kqkv<<<384, 256, 0, stream>>>(xT, Wqkv_b, bq, bk, bv, qT, kTp, vp, b);
    }
    kattn<<<512, 256, 0, stream>>>(qT, kTp, vp, Wo_b, mask, bo, y);
}

// Round 3
// 186.970 us; speedup vs baseline: 1.7969x; 1.0865x over previous
//
#include <hip/hip_runtime.h>
#include <hip/hip_bf16.h>

typedef __attribute__((ext_vector_type(8))) short short8;
typedef __attribute__((ext_vector_type(4))) float f32x4;
typedef __attribute__((ext_vector_type(4))) int int4v;

#define DI __device__ __forceinline__

constexpr int Bq = 4, Cc = 512, Ss = 8192, Ee = 256;
constexpr int SP = 8448;   // padded s extent (128 + 8192 + 128)

DI unsigned short f2bf(float f) {
    unsigned int u = __float_as_uint(f);
    unsigned int r = u + 0x7fffu + ((u >> 16) & 1u);
    return (unsigned short)(r >> 16);
}

union U16x8 { int4v v; unsigned short u[8]; };

DI void gll16(const void* g, void* l) {
    __builtin_amdgcn_global_load_lds(
        (const __attribute__((address_space(1))) unsigned int*)g,
        (__attribute__((address_space(3))) unsigned int*)l, 16, 0, 0);
}

DI unsigned pkbf(float lo, float hi) {
    unsigned r;
    asm("v_cvt_pk_bf16_f32 %0, %1, %2" : "=v"(r) : "v"(lo), "v"(hi));
    return r;
}

DI short8 mk8(unsigned a, unsigned b, unsigned c, unsigned d) {
    int4v v; v[0] = (int)a; v[1] = (int)b; v[2] = (int)c; v[3] = (int)d;
    union { int4v i; short8 s; } U; U.i = v; return U.s;
}

DI f32x4 max4(f32x4 a, f32x4 b) {
    f32x4 r;
    r[0] = fmaxf(a[0], b[0]); r[1] = fmaxf(a[1], b[1]);
    r[2] = fmaxf(a[2], b[2]); r[3] = fmaxf(a[3], b[3]);
    return r;
}

DI float gelu_t(float x) {
    float x2 = x * x;
    float z = x * (0.7978845608f + 0.0356774081f * x2);
    float az = fabsf(z);
    float e = __expf(-2.f * az);
    float th = (1.f - e) / (1.f + e);
    th = (z < 0.f) ? -th : th;
    return 0.5f * x * (1.f + th);
}

// sigma on 5-bit index k = [G1 G0 j2 j1 j0] -> [j2 G1 G0 j1 j0]; sigma^3 = id
DI int SIG(int k)  { return ((k & 4) << 2) | ((k & 24) >> 1) | (k & 3); }
DI int SIG2(int k) { return SIG(SIG(k)); }

// ---------- convert weights to bf16: Wqkv [768][512], Wo [512][256] (Wo sigma-permuted cols) ----------
__global__ __launch_bounds__(256) void kconv_w(
    const float* __restrict__ Wq, const float* __restrict__ Wk, const float* __restrict__ Wv,
    const float* __restrict__ Wo, unsigned short* __restrict__ Wqkv_b, unsigned short* __restrict__ Wo_b)
{
    int i = blockIdx.x * 256 + threadIdx.x;
    if (i < 768 * 512) {
        int m = i >> 9, c = i & 511;
        const float* src = (m < 256) ? Wq : ((m < 512) ? Wk : Wv);
        Wqkv_b[i] = f2bf(src[(m & 255) * 512 + c]);
    }
    if (i < 512 * 256) {
        int kap = i & 255;
        int src = (i & ~255) | (kap & ~31) | SIG(kap & 31);
        Wo_b[i] = f2bf(Wo[src]);
    }
}

// ---------- zero pads of kTp (rows) and vp (cols) ----------
__global__ __launch_bounds__(256) void kzero(unsigned short* __restrict__ kTp, unsigned short* __restrict__ vp)
{
    int i = blockIdx.x * 256 + threadIdx.x;
    int4v z = {0, 0, 0, 0};
    if (i < 32768) {
        int b = i >> 13, r = i & 8191;
        int side = r >> 12, off = r & 4095;
        *(int4v*)(kTp + (long)b * SP * 256 + (long)(side ? 8320 : 0) * 256 + off * 8) = z;
    } else {
        int j = i - 32768;
        int b = j >> 13, r = j & 8191;
        int row = r >> 5, side = (r >> 4) & 1, sc = r & 15;
        *(int4v*)(vp + ((long)b * 256 + row) * SP + side * 8320 + sc * 8) = z;
    }
}

// ---------- transpose x1[b] (C,S) f32 -> xT (S,C) bf16 ----------
__global__ __launch_bounds__(256) void ktr_x(const float* __restrict__ x1b, unsigned short* __restrict__ xT)
{
    __shared__ unsigned short tile[64][72];
    int t = threadIdx.x;
    int bs = blockIdx.x & 127, bc = blockIdx.x >> 7;
    int s0 = bs * 64, c0 = bc * 64;
    int cl = t >> 4, sl = (t & 15) * 4;
    for (int it = 0; it < 4; ++it) {
        int c = cl + it * 16;
        float4 vv = *(const float4*)(x1b + (long)(c0 + c) * Ss + s0 + sl);
        tile[c][sl + 0] = f2bf(vv.x);
        tile[c][sl + 1] = f2bf(vv.y);
        tile[c][sl + 2] = f2bf(vv.z);
        tile[c][sl + 3] = f2bf(vv.w);
    }
    __syncthreads();
    int s_loc = t >> 2, cseg = (t & 3) * 16;
    for (int half = 0; half < 2; ++half) {
        U16x8 u;
        for (int j = 0; j < 8; ++j) u.u[j] = tile[cseg + half * 8 + j][s_loc];
        *(int4v*)(xT + (long)(s0 + s_loc) * Cc + c0 + cseg + half * 8) = u.v;
    }
}

// ---------- QKV GEMM (per batch): q,k -> [s][e], v -> [e][s] with sigma-permuted cols ----------
__global__ __launch_bounds__(256) void kqkv(
    const unsigned short* __restrict__ xT, const unsigned short* __restrict__ Wqkv,
    const float* __restrict__ bq, const float* __restrict__ bk, const float* __restrict__ bv,
    unsigned short* __restrict__ qT, unsigned short* __restrict__ kTp, unsigned short* __restrict__ vp,
    int b)
{
    __shared__ int4v As[1024], Bs[1024];
    int wg = blockIdx.x;
    int type = wg >> 7, id = wg & 127;     // 0=q 1=k 2=v
    const unsigned short *A, *Bt; unsigned short* Op;
    long opitch; const float* bias; bool biasRow;
    if (type < 2) {
        int mt = id >> 1, nt = id & 1;
        A  = xT + (long)(mt * 128) * 512;
        Bt = Wqkv + (long)(type * 256 + nt * 128) * 512;
        if (type == 0)
            Op = qT + (long)b * Ss * Ee + (long)(mt * 128) * Ee + nt * 128;
        else
            Op = kTp + (long)b * SP * Ee + (long)(128 + mt * 128) * Ee + nt * 128;
        opitch = Ee;
        bias = (type ? bk : bq) + nt * 128;
        biasRow = false;
    } else {
        int mt = id >> 6, nt = id & 63;
        A  = Wqkv + (long)(512 + mt * 128) * 512;
        Bt = xT + (long)(nt * 128) * 512;
        Op = vp + (long)b * Ee * SP + (long)(mt * 128) * SP + 128 + nt * 128;
        opitch = SP;
        bias = bv + mt * 128;
        biasRow = true;
    }
    int t = threadIdx.x, lane = t & 63, wv = t >> 6;
    int wr = (wv >> 1) * 64, wc = (wv & 1) * 64;
    f32x4 acc[4][4] = {};
    for (int kk = 0; kk < 8; ++kk) {
        __syncthreads();
        for (int i = 0; i < 4; ++i) {
            int seg = t + 256 * i;
            int row = seg >> 3, cs = seg & 7;
            int4v va = *(const int4v*)(A  + (long)row * 512 + kk * 64 + cs * 8);
            int4v vb = *(const int4v*)(Bt + (long)row * 512 + kk * 64 + cs * 8);
            As[row * 8 + (cs ^ (row & 7))] = va;
            Bs[row * 8 + (cs ^ (row & 7))] = vb;
        }
        __syncthreads();
        for (int ks = 0; ks < 2; ++ks) {
            int csk = ks * 4 + (lane >> 4);
            short8 af[4], bfr[4];
            #pragma unroll
            for (int mi = 0; mi < 4; ++mi) {
                int m = wr + mi * 16 + (lane & 15);
                af[mi] = *(const short8*)&As[m * 8 + (csk ^ (m & 7))];
            }
            #pragma unroll
            for (int ni = 0; ni < 4; ++ni) {
                int nn = wc + ni * 16 + (lane & 15);
                bfr[ni] = *(const short8*)&Bs[nn * 8 + (csk ^ (nn & 7))];
            }
            #pragma unroll
            for (int mi = 0; mi < 4; ++mi)
                #pragma unroll
                for (int ni = 0; ni < 4; ++ni)
                    acc[mi][ni] = __builtin_amdgcn_mfma_f32_16x16x32_bf16(af[mi], bfr[ni], acc[mi][ni], 0, 0, 0);
        }
    }
    for (int mi = 0; mi < 4; ++mi)
        for (int ni = 0; ni < 4; ++ni) {
            int mrow = wr + mi * 16 + ((lane >> 4) * 4);
            int ncol = wc + ni * 16 + (lane & 15);
            int nc2 = biasRow ? ((ncol & ~31) | SIG2(ncol & 31)) : ncol;
            for (int r = 0; r < 4; ++r) {
                float bval = biasRow ? bias[mrow + r] : bias[ncol];
                Op[(long)(mrow + r) * opitch + nc2] = f2bf(acc[mi][ni][r] + bval);
            }
        }
}

// ---------- fused attention + gelu + output projection ----------
// grid 256 = (b,n,qhalf) XCD-paired; 4 waves; wave owns 32 q rows (2x 16x16 q-subtiles);
// swapped QK^T -> in-lane softmax; sigma-permuted V/Wo -> zero-shuffle P/h fragments.
__global__ __launch_bounds__(256, 1) void kattn(
    const unsigned short* __restrict__ qT, const unsigned short* __restrict__ kTp,
    const unsigned short* __restrict__ vp,  const unsigned short* __restrict__ Wo_b,
    const float* __restrict__ mask, const float* __restrict__ bo,
    float* __restrict__ y)
{
    // LDS: K dbuf 2x32KB | V dbuf 2x32KB | fmask 2KB | lmask 2KB | bo 2KB
    __shared__ __align__(16) char SH[137216];
    float* fmaskL = (float*)(SH + 131072);
    float* lmaskL = (float*)(SH + 133120);
    float* boL    = (float*)(SH + 135168);

    int t = threadIdx.x, lane = t & 63, wv = t >> 6;
    int G = lane >> 4, l15 = lane & 15;

    // XCD swizzle: pair (qh=0,1) of same (b,n) onto same XCD (assumes phys%8 = XCD)
    int phys = blockIdx.x;
    int xx = phys & 7, kk2 = phys >> 3;
    int L = ((xx + 8 * (kk2 >> 1)) << 1) | (kk2 & 1);
    int qh = L & 1, n = (L >> 1) & 31, b = L >> 6;
    int sqw = n * 256 + qh * 128 + wv * 32;

    // --- Q fragments to regs (B-operand: rows = q, k = e)
    short8 qfrag[2][8];
    #pragma unroll
    for (int qs = 0; qs < 2; ++qs)
        #pragma unroll
        for (int s = 0; s < 8; ++s)
            qfrag[qs][s] = *(const short8*)(qT + ((long)b * Ss + sqw + qs * 16 + l15) * 256 + 32 * s + 8 * G);

    // --- window masks + bias
    for (int i = t; i < 512; i += 256) {
        int sw = n * 256 - 128 + i;
        float f = 0.f;
        if (i != 511 && sw >= 0 && sw < Ss) f = mask[(long)b * Ss + sw];
        fmaskL[i] = f;
        lmaskL[i] = __logf(f + 1e-6f);
    }
    if (t < 128) ((float4*)boL)[t] = ((const float4*)bo)[t];

    // --- staging source pointers (pre-swizzled global, linear LDS dest)
    const unsigned short* ksrcp[8];
    const unsigned short* vsrcp[8];
    #pragma unroll
    for (int i = 0; i < 8; ++i) {
        int krow = wv * 16 + i * 2 + (lane >> 5);
        ksrcp[i] = kTp + ((long)b * SP + n * 256 + krow) * 256 + (((lane & 31) ^ (krow & 7)) * 8);
        int erow = wv * 64 + i * 8 + (lane >> 3);
        vsrcp[i] = vp + ((long)b * 256 + erow) * SP + n * 256 + (((lane & 7) ^ ((lane >> 3) & 7)) * 8);
    }

#define STAGE(CH, BUF) {                                                     \
        char* kl = SH + (BUF) * 32768 + wv * (16 * 512);                     \
        char* vl = SH + 65536 + (BUF) * 32768 + wv * (64 * 128);             \
        long ko = (long)(CH) * 64 * 256;                                     \
        int  vo = (CH) * 64;                                                 \
        _Pragma("unroll")                                                    \
        for (int i = 0; i < 8; ++i) gll16(ksrcp[i] + ko, kl + i * (2 * 512));\
        _Pragma("unroll")                                                    \
        for (int i = 0; i < 8; ++i) gll16(vsrcp[i] + vo, vl + i * (8 * 128));\
    }

    STAGE(0, 0)
    STAGE(1, 1)
    asm volatile("s_waitcnt vmcnt(16) lgkmcnt(0)" ::: "memory");
    __builtin_amdgcn_s_barrier();

    float mrun[2] = {-1e30f, -1e30f}, lrun[2] = {0.f, 0.f};
    f32x4 oacc[2][16] = {};

    #pragma unroll 2
    for (int ch = 0; ch < 8; ++ch) {
        const char* KB = SH + (ch & 1) * 32768;
        const char* VB = SH + 65536 + (ch & 1) * 32768;

        // --- energy: E^T[w][q] = mfma(K, Q); 64 keys = 4 w-tiles
        f32x4 eacc[2][4] = {};
        #pragma unroll
        for (int s = 0; s < 8; ++s) {
            short8 kf[4];
            #pragma unroll
            for (int tt = 0; tt < 4; ++tt)
                kf[tt] = *(const short8*)(KB + (16 * tt + l15) * 512 + (((4 * s + G) ^ (l15 & 7)) * 16));
            #pragma unroll
            for (int tt = 0; tt < 4; ++tt) {
                eacc[0][tt] = __builtin_amdgcn_mfma_f32_16x16x32_bf16(kf[tt], qfrag[0][s], eacc[0][tt], 0, 0, 0);
                eacc[1][tt] = __builtin_amdgcn_mfma_f32_16x16x32_bf16(kf[tt], qfrag[1][s], eacc[1][tt], 0, 0, 0);
            }
        }

        int w0 = ch * 64;
        f32x4 lm[4], fm[4];
        #pragma unroll
        for (int tt = 0; tt < 4; ++tt) {
            lm[tt] = *(const f32x4*)&lmaskL[w0 + 16 * tt + 4 * G];
            fm[tt] = *(const f32x4*)&fmaskL[w0 + 16 * tt + 4 * G];
        }

        // --- in-lane online softmax (q = l15, per qs)
        f32x4 ev[2][4];
        float cm[2];
        #pragma unroll
        for (int qs = 0; qs < 2; ++qs) {
            f32x4 m4;
            #pragma unroll
            for (int tt = 0; tt < 4; ++tt) {
                ev[qs][tt] = eacc[qs][tt] * 0.0625f + lm[tt];
                m4 = tt ? max4(m4, ev[qs][tt]) : ev[qs][tt];
            }
            float c = fmaxf(fmaxf(m4[0], m4[1]), fmaxf(m4[2], m4[3]));
            c = fmaxf(c, __shfl_xor(c, 16));
            c = fmaxf(c, __shfl_xor(c, 32));
            cm[qs] = c;
        }
        bool big = (cm[0] > mrun[0] + 8.f) || (cm[1] > mrun[1] + 8.f);
        if (__any(big)) {
            #pragma unroll
            for (int qs = 0; qs < 2; ++qs) {
                float mn = fmaxf(mrun[qs], cm[qs]);
                float sc = __expf(mrun[qs] - mn);
                mrun[qs] = mn; lrun[qs] *= sc;
                #pragma unroll
                for (int et = 0; et < 16; ++et) oacc[qs][et] *= sc;
            }
        }

        unsigned pc[2][8];
        #pragma unroll
        for (int qs = 0; qs < 2; ++qs) {
            float ssum = 0.f;
            #pragma unroll
            for (int tt = 0; tt < 4; ++tt) {
                f32x4 p;
                p[0] = __expf(ev[qs][tt][0] - mrun[qs]);
                p[1] = __expf(ev[qs][tt][1] - mrun[qs]);
                p[2] = __expf(ev[qs][tt][2] - mrun[qs]);
                p[3] = __expf(ev[qs][tt][3] - mrun[qs]);
                ssum += (p[0] + p[1]) + (p[2] + p[3]);
                f32x4 pf = p * fm[tt];
                pc[qs][2 * tt]     = pkbf(pf[0], pf[1]);
                pc[qs][2 * tt + 1] = pkbf(pf[2], pf[3]);
            }
            ssum += __shfl_xor(ssum, 16);
            ssum += __shfl_xor(ssum, 32);
            lrun[qs] += ssum;
        }

        // --- PV: O^T[e][q] += mfma(V~, P~); sigma-permute makes pc the exact B-fragment
        #pragma unroll
        for (int s = 0; s < 2; ++s) {
            short8 pf0 = mk8(pc[0][4 * s], pc[0][4 * s + 1], pc[0][4 * s + 2], pc[0][4 * s + 3]);
            short8 pf1 = mk8(pc[1][4 * s], pc[1][4 * s + 1], pc[1][4 * s + 2], pc[1][4 * s + 3]);
            #pragma unroll
            for (int et = 0; et < 16; ++et) {
                short8 vf = *(const short8*)(VB + (16 * et + l15) * 128 + (((4 * s + G) ^ (l15 & 7)) * 16));
                oacc[0][et] = __builtin_amdgcn_mfma_f32_16x16x32_bf16(vf, pf0, oacc[0][et], 0, 0, 0);
                oacc[1][et] = __builtin_amdgcn_mfma_f32_16x16x32_bf16(vf, pf1, oacc[1][et], 0, 0, 0);
            }
        }

        asm volatile("s_waitcnt lgkmcnt(0)" ::: "memory");
        __builtin_amdgcn_s_barrier();
        if (ch < 6) {
            STAGE(ch + 2, ch & 1)
            asm volatile("s_waitcnt vmcnt(16)" ::: "memory");
        } else if (ch == 6) {
            asm volatile("s_waitcnt vmcnt(0)" ::: "memory");
        }
        __builtin_amdgcn_s_barrier();
    }

    // --- epilogue (barrier-free): 1/l, gelu, pack h fragments in-register
    float linv[2] = {1.f / lrun[0], 1.f / lrun[1]};
    unsigned hc[2][32];
    #pragma unroll
    for (int qs = 0; qs < 2; ++qs)
        #pragma unroll
        for (int et = 0; et < 16; ++et) {
            f32x4 xv = oacc[qs][et] * linv[qs];
            hc[qs][2 * et]     = pkbf(gelu_t(xv[0]), gelu_t(xv[1]));
            hc[qs][2 * et + 1] = pkbf(gelu_t(xv[2]), gelu_t(xv[3]));
        }

    float ym[2] = { fmaskL[128 + qh * 128 + wv * 32 + l15],
                    fmaskL[128 + qh * 128 + wv * 32 + 16 + l15] };

    // --- projection: y[o][s] = Wo~ . h~ + bo (Wo gathered from L2, sigma-permuted)
    #pragma unroll 2
    for (int ot = 0; ot < 32; ++ot) {
        short8 wf[8];
        #pragma unroll
        for (int s = 0; s < 8; ++s)
            wf[s] = *(const short8*)(Wo_b + ((long)(16 * ot + l15)) * 256 + 32 * s + 8 * G);
        f32x4 pacc0 = {}, pacc1 = {};
        #pragma unroll
        for (int s = 0; s < 8; ++s) {
            short8 h0 = mk8(hc[0][4 * s], hc[0][4 * s + 1], hc[0][4 * s + 2], hc[0][4 * s + 3]);
            short8 h1 = mk8(hc[1][4 * s], hc[1][4 * s + 1], hc[1][4 * s + 2], hc[1][4 * s + 3]);
            pacc0 = __builtin_amdgcn_mfma_f32_16x16x32_bf16(wf[s], h0, pacc0, 0, 0, 0);
            pacc1 = __builtin_amdgcn_mfma_f32_16x16x32_bf16(wf[s], h1, pacc1, 0, 0, 0);
        }
        f32x4 bo4 = *(const f32x4*)&boL[16 * ot + 4 * G];
        #pragma unroll
        for (int r = 0; r < 4; ++r) {
            long orow = (long)b * Cc + 16 * ot + 4 * G + r;
            y[orow * Ss + sqw + l15]      = (pacc0[r] + bo4[r]) * ym[0];
            y[orow * Ss + sqw + 16 + l15] = (pacc1[r] + bo4[r]) * ym[1];
        }
    }
#undef STAGE
}

extern "C" void kernel_launch(void* const* d_in, const int* in_sizes, int n_in,
                              void* d_out, int out_size, void* d_ws, size_t ws_size,
                              hipStream_t stream)
{
    const float* x1   = (const float*)d_in[0];
    const float* mask = (const float*)d_in[1];
    const float* Wq   = (const float*)d_in[2];
    const float* bq   = (const float*)d_in[3];
    const float* Wk   = (const float*)d_in[4];
    const float* bk   = (const float*)d_in[5];
    const float* Wv   = (const float*)d_in[6];
    const float* bv   = (const float*)d_in[7];
    const float* Wo   = (const float*)d_in[8];
    const float* bo   = (const float*)d_in[9];
    float* y = (float*)d_out;

    // ws layout (bf16):
    // Wqkv_b 786432 | Wo_b 262144 | xT 8388608 | qT 16777216 | kTp 17301504 | vp 17301504
    if (ws_size < 60817408u) return;
    char* w = (char*)d_ws;
    unsigned short* Wqkv_b = (unsigned short*)(w);
    unsigned short* Wo_b   = (unsigned short*)(w + 786432);
    unsigned short* xT     = (unsigned short*)(w + 1048576);
    unsigned short* qT     = (unsigned short*)(w + 9437184);
    unsigned short* kTp    = (unsigned short*)(w + 26214400);
    unsigned short* vp     = (unsigned short*)(w + 43515904);

    kconv_w<<<1536, 256, 0, stream>>>(Wq, Wk, Wv, Wo, Wqkv_b, Wo_b);
    kzero<<<256, 256, 0, stream>>>(kTp, vp);
    for (int b = 0; b < 4; ++b) {
        ktr_x<<<1024, 256, 0, stream>>>(x1 + (long)b * Cc * Ss, xT);
        kqkv<<<384, 256, 0, stream>>>(xT, Wqkv_b, bq, bk, bv, qT, kTp, vp, b);
    }
    kattn<<<256, 256, 0, stream>>>(qT, kTp, vp, Wo_b, mask, bo, y);
}

// Round 4
// 155.774 us; speedup vs baseline: 2.1568x; 1.2003x over previous
//
#include <hip/hip_runtime.h>
#include <hip/hip_bf16.h>

typedef __attribute__((ext_vector_type(8))) short short8;
typedef __attribute__((ext_vector_type(4))) float f32x4;
typedef __attribute__((ext_vector_type(4))) int int4v;

#define DI __device__ __forceinline__

constexpr int Bq = 4, Cc = 512, Ss = 8192, Ee = 256;
constexpr int SP = 8448;   // padded s extent (128 + 8192 + 128)

DI unsigned short f2bf(float f) {
    unsigned int u = __float_as_uint(f);
    unsigned int r = u + 0x7fffu + ((u >> 16) & 1u);
    return (unsigned short)(r >> 16);
}

union U16x8 { int4v v; unsigned short u[8]; };

DI void gll16(const void* g, void* l) {
    __builtin_amdgcn_global_load_lds(
        (const __attribute__((address_space(1))) unsigned int*)g,
        (__attribute__((address_space(3))) unsigned int*)l, 16, 0, 0);
}

DI unsigned pkbf(float lo, float hi) {
    unsigned r;
    asm("v_cvt_pk_bf16_f32 %0, %1, %2" : "=v"(r) : "v"(lo), "v"(hi));
    return r;
}

DI short8 mk8(unsigned a, unsigned b, unsigned c, unsigned d) {
    int4v v; v[0] = (int)a; v[1] = (int)b; v[2] = (int)c; v[3] = (int)d;
    union { int4v i; short8 s; } U; U.i = v; return U.s;
}

DI f32x4 max4(f32x4 a, f32x4 b) {
    f32x4 r;
    r[0] = fmaxf(a[0], b[0]); r[1] = fmaxf(a[1], b[1]);
    r[2] = fmaxf(a[2], b[2]); r[3] = fmaxf(a[3], b[3]);
    return r;
}

DI float gelu_t(float x) {
    float x2 = x * x;
    float z = x * (0.7978845608f + 0.0356774081f * x2);
    float az = fabsf(z);
    float e = __expf(-2.f * az);
    float th = (1.f - e) / (1.f + e);
    th = (z < 0.f) ? -th : th;
    return 0.5f * x * (1.f + th);
}

// sigma on 5-bit index k = [G1 G0 j2 j1 j0] -> [j2 G1 G0 j1 j0]; sigma^3 = id
DI int SIG(int k)  { return ((k & 4) << 2) | ((k & 24) >> 1) | (k & 3); }
DI int SIG2(int k) { return SIG(SIG(k)); }

// ---------- convert weights to bf16: Wqkv [768][512], Wo [512][256] (Wo sigma-permuted cols) ----------
__global__ __launch_bounds__(256) void kconv_w(
    const float* __restrict__ Wq, const float* __restrict__ Wk, const float* __restrict__ Wv,
    const float* __restrict__ Wo, unsigned short* __restrict__ Wqkv_b, unsigned short* __restrict__ Wo_b)
{
    int i = blockIdx.x * 256 + threadIdx.x;
    if (i < 768 * 512) {
        int m = i >> 9, c = i & 511;
        const float* src = (m < 256) ? Wq : ((m < 512) ? Wk : Wv);
        Wqkv_b[i] = f2bf(src[(m & 255) * 512 + c]);
    }
    if (i < 512 * 256) {
        int kap = i & 255;
        int src = (i & ~255) | (kap & ~31) | SIG(kap & 31);
        Wo_b[i] = f2bf(Wo[src]);
    }
}

// ---------- zero pads of kTp (rows) and vp (cols) ----------
__global__ __launch_bounds__(256) void kzero(unsigned short* __restrict__ kTp, unsigned short* __restrict__ vp)
{
    int i = blockIdx.x * 256 + threadIdx.x;
    int4v z = {0, 0, 0, 0};
    if (i < 32768) {
        int b = i >> 13, r = i & 8191;
        int side = r >> 12, off = r & 4095;
        *(int4v*)(kTp + (long)b * SP * 256 + (long)(side ? 8320 : 0) * 256 + off * 8) = z;
    } else {
        int j = i - 32768;
        int b = j >> 13, r = j & 8191;
        int row = r >> 5, side = (r >> 4) & 1, sc = r & 15;
        *(int4v*)(vp + ((long)b * 256 + row) * SP + side * 8320 + sc * 8) = z;
    }
}

// ---------- transpose x1[b] (C,S) f32 -> xT (S,C) bf16 ----------
__global__ __launch_bounds__(256) void ktr_x(const float* __restrict__ x1b, unsigned short* __restrict__ xT)
{
    __shared__ unsigned short tile[64][72];
    int t = threadIdx.x;
    int bs = blockIdx.x & 127, bc = blockIdx.x >> 7;
    int s0 = bs * 64, c0 = bc * 64;
    int cl = t >> 4, sl = (t & 15) * 4;
    for (int it = 0; it < 4; ++it) {
        int c = cl + it * 16;
        float4 vv = *(const float4*)(x1b + (long)(c0 + c) * Ss + s0 + sl);
        tile[c][sl + 0] = f2bf(vv.x);
        tile[c][sl + 1] = f2bf(vv.y);
        tile[c][sl + 2] = f2bf(vv.z);
        tile[c][sl + 3] = f2bf(vv.w);
    }
    __syncthreads();
    int s_loc = t >> 2, cseg = (t & 3) * 16;
    for (int half = 0; half < 2; ++half) {
        U16x8 u;
        for (int j = 0; j < 8; ++j) u.u[j] = tile[cseg + half * 8 + j][s_loc];
        *(int4v*)(xT + (long)(s0 + s_loc) * Cc + c0 + cseg + half * 8) = u.v;
    }
}

// ---------- QKV GEMM (per batch): q,k -> [s][e], v -> [e][s] with sigma-permuted cols ----------
__global__ __launch_bounds__(256) void kqkv(
    const unsigned short* __restrict__ xT, const unsigned short* __restrict__ Wqkv,
    const float* __restrict__ bq, const float* __restrict__ bk, const float* __restrict__ bv,
    unsigned short* __restrict__ qT, unsigned short* __restrict__ kTp, unsigned short* __restrict__ vp,
    int b)
{
    __shared__ int4v As[1024], Bs[1024];
    int wg = blockIdx.x;
    int type = wg >> 7, id = wg & 127;     // 0=q 1=k 2=v
    const unsigned short *A, *Bt; unsigned short* Op;
    long opitch; const float* bias; bool biasRow;
    if (type < 2) {
        int mt = id >> 1, nt = id & 1;
        A  = xT + (long)(mt * 128) * 512;
        Bt = Wqkv + (long)(type * 256 + nt * 128) * 512;
        if (type == 0)
            Op = qT + (long)b * Ss * Ee + (long)(mt * 128) * Ee + nt * 128;
        else
            Op = kTp + (long)b * SP * Ee + (long)(128 + mt * 128) * Ee + nt * 128;
        opitch = Ee;
        bias = (type ? bk : bq) + nt * 128;
        biasRow = false;
    } else {
        int mt = id >> 6, nt = id & 63;
        A  = Wqkv + (long)(512 + mt * 128) * 512;
        Bt = xT + (long)(nt * 128) * 512;
        Op = vp + (long)b * Ee * SP + (long)(mt * 128) * SP + 128 + nt * 128;
        opitch = SP;
        bias = bv + mt * 128;
        biasRow = true;
    }
    int t = threadIdx.x, lane = t & 63, wv = t >> 6;
    int wr = (wv >> 1) * 64, wc = (wv & 1) * 64;
    f32x4 acc[4][4] = {};
    for (int kk = 0; kk < 8; ++kk) {
        __syncthreads();
        for (int i = 0; i < 4; ++i) {
            int seg = t + 256 * i;
            int row = seg >> 3, cs = seg & 7;
            int4v va = *(const int4v*)(A  + (long)row * 512 + kk * 64 + cs * 8);
            int4v vb = *(const int4v*)(Bt + (long)row * 512 + kk * 64 + cs * 8);
            As[row * 8 + (cs ^ (row & 7))] = va;
            Bs[row * 8 + (cs ^ (row & 7))] = vb;
        }
        __syncthreads();
        for (int ks = 0; ks < 2; ++ks) {
            int csk = ks * 4 + (lane >> 4);
            short8 af[4], bfr[4];
            #pragma unroll
            for (int mi = 0; mi < 4; ++mi) {
                int m = wr + mi * 16 + (lane & 15);
                af[mi] = *(const short8*)&As[m * 8 + (csk ^ (m & 7))];
            }
            #pragma unroll
            for (int ni = 0; ni < 4; ++ni) {
                int nn = wc + ni * 16 + (lane & 15);
                bfr[ni] = *(const short8*)&Bs[nn * 8 + (csk ^ (nn & 7))];
            }
            #pragma unroll
            for (int mi = 0; mi < 4; ++mi)
                #pragma unroll
                for (int ni = 0; ni < 4; ++ni)
                    acc[mi][ni] = __builtin_amdgcn_mfma_f32_16x16x32_bf16(af[mi], bfr[ni], acc[mi][ni], 0, 0, 0);
        }
    }
    for (int mi = 0; mi < 4; ++mi)
        for (int ni = 0; ni < 4; ++ni) {
            int mrow = wr + mi * 16 + ((lane >> 4) * 4);
            int ncol = wc + ni * 16 + (lane & 15);
            int nc2 = biasRow ? ((ncol & ~31) | SIG2(ncol & 31)) : ncol;
            for (int r = 0; r < 4; ++r) {
                float bval = biasRow ? bias[mrow + r] : bias[ncol];
                Op[(long)(mrow + r) * opitch + nc2] = f2bf(acc[mi][ni][r] + bval);
            }
        }
}

// ---------- fused attention + gelu + output projection ----------
// grid 256 = (b,n,qhalf) XCD-paired; 8 waves x 16 q rows; swapped QK^T -> in-lane softmax;
// sigma-permuted V/Wo -> zero-shuffle P/h fragments; LDS-staged Wo projection.
__global__ __launch_bounds__(512, 1) void kattn(
    const unsigned short* __restrict__ qT, const unsigned short* __restrict__ kTp,
    const unsigned short* __restrict__ vp,  const unsigned short* __restrict__ Wo_b,
    const float* __restrict__ mask, const float* __restrict__ bo,
    float* __restrict__ y)
{
    // LDS: K dbuf 2x32KB (also Wo dbuf in proj) | V dbuf 2x32KB | fmask 2KB | lmask 2KB | bo 2KB
    __shared__ __align__(16) char SH[137216];
    float* fmaskL = (float*)(SH + 131072);
    float* lmaskL = (float*)(SH + 133120);
    float* boL    = (float*)(SH + 135168);

    int t = threadIdx.x, lane = t & 63, wv = t >> 6;   // wv in [0,8)
    int G = lane >> 4, l15 = lane & 15;

    // XCD swizzle: pair (qh=0,1) of same (b,n) onto same XCD (assumes phys%8 = XCD)
    int phys = blockIdx.x;
    int xx = phys & 7, kk2 = phys >> 3;
    int L = ((xx + 8 * (kk2 >> 1)) << 1) | (kk2 & 1);
    int qh = L & 1, n = (L >> 1) & 31, b = L >> 6;
    int sqw = n * 256 + qh * 128 + wv * 16;

    // --- Q fragments direct from global (B-operand: rows = q, k = e)
    short8 qfrag[8];
    #pragma unroll
    for (int s = 0; s < 8; ++s)
        qfrag[s] = *(const short8*)(qT + ((long)b * Ss + sqw + l15) * 256 + 32 * s + 8 * G);

    // --- window masks + bias
    {
        int i = t;
        int sw = n * 256 - 128 + i;
        float f = 0.f;
        if (i != 511 && sw >= 0 && sw < Ss) f = mask[(long)b * Ss + sw];
        fmaskL[i] = f;
        lmaskL[i] = __logf(f + 1e-6f);
    }
    if (t < 128) ((float4*)boL)[t] = ((const float4*)bo)[t];

    // --- staging source pointers (pre-swizzled global, linear LDS dest)
    const unsigned short* ksrcp[4];
    const unsigned short* vsrcp[4];
    #pragma unroll
    for (int i = 0; i < 4; ++i) {
        int krow = wv * 8 + i * 2 + (lane >> 5);
        ksrcp[i] = kTp + ((long)b * SP + n * 256 + krow) * 256 + (((lane & 31) ^ (krow & 7)) * 8);
        int erow = wv * 32 + i * 8 + (lane >> 3);
        vsrcp[i] = vp + ((long)b * 256 + erow) * SP + n * 256 + (((lane & 7) ^ ((lane >> 3) & 7)) * 8);
    }

#define STAGE(CH, BUF) {                                                      \
        char* kl = SH + (BUF) * 32768 + wv * 4096;                            \
        char* vl = SH + 65536 + (BUF) * 32768 + wv * 4096;                    \
        _Pragma("unroll")                                                     \
        for (int i = 0; i < 4; ++i) gll16(ksrcp[i] + (long)(CH) * 16384, kl + i * 1024); \
        _Pragma("unroll")                                                     \
        for (int i = 0; i < 4; ++i) gll16(vsrcp[i] + (CH) * 64, vl + i * 1024);          \
    }

    STAGE(0, 0)
    STAGE(1, 1)
    asm volatile("s_waitcnt vmcnt(8) lgkmcnt(0)" ::: "memory");
    __builtin_amdgcn_s_barrier();

    float mrun = -1e30f, lrun = 0.f;
    f32x4 oacc[16] = {};

    for (int ch = 0; ch < 8; ++ch) {
        const char* KB = SH + (ch & 1) * 32768;
        const char* VB = SH + 65536 + (ch & 1) * 32768;

        // --- energy: E^T[w][q] = mfma(K, Q); 64 keys = 4 w-tiles
        f32x4 eacc[4] = {};
        __builtin_amdgcn_s_setprio(1);
        #pragma unroll
        for (int s = 0; s < 8; ++s) {
            short8 kf[4];
            #pragma unroll
            for (int tt = 0; tt < 4; ++tt)
                kf[tt] = *(const short8*)(KB + (16 * tt + l15) * 512 + (((4 * s + G) ^ (l15 & 7)) * 16));
            #pragma unroll
            for (int tt = 0; tt < 4; ++tt)
                eacc[tt] = __builtin_amdgcn_mfma_f32_16x16x32_bf16(kf[tt], qfrag[s], eacc[tt], 0, 0, 0);
        }
        __builtin_amdgcn_s_setprio(0);

        int w0 = ch * 64;
        f32x4 lm[4], fm[4];
        #pragma unroll
        for (int tt = 0; tt < 4; ++tt) {
            lm[tt] = *(const f32x4*)&lmaskL[w0 + 16 * tt + 4 * G];
            fm[tt] = *(const f32x4*)&fmaskL[w0 + 16 * tt + 4 * G];
        }

        // --- in-lane online softmax (q = l15)
        f32x4 ev[4];
        f32x4 m4;
        #pragma unroll
        for (int tt = 0; tt < 4; ++tt) {
            ev[tt] = eacc[tt] * 0.0625f + lm[tt];
            m4 = tt ? max4(m4, ev[tt]) : ev[tt];
        }
        float cm = fmaxf(fmaxf(m4[0], m4[1]), fmaxf(m4[2], m4[3]));
        cm = fmaxf(cm, __shfl_xor(cm, 16));
        cm = fmaxf(cm, __shfl_xor(cm, 32));
        if (__any(cm > mrun + 8.f)) {
            float mn = fmaxf(mrun, cm);
            float sc = __expf(mrun - mn);
            mrun = mn; lrun *= sc;
            #pragma unroll
            for (int et = 0; et < 16; ++et) oacc[et] *= sc;
        }

        unsigned pc[8];
        float ssum = 0.f;
        #pragma unroll
        for (int tt = 0; tt < 4; ++tt) {
            f32x4 p;
            p[0] = __expf(ev[tt][0] - mrun);
            p[1] = __expf(ev[tt][1] - mrun);
            p[2] = __expf(ev[tt][2] - mrun);
            p[3] = __expf(ev[tt][3] - mrun);
            ssum += (p[0] + p[1]) + (p[2] + p[3]);
            f32x4 pf = p * fm[tt];
            pc[2 * tt]     = pkbf(pf[0], pf[1]);
            pc[2 * tt + 1] = pkbf(pf[2], pf[3]);
        }
        ssum += __shfl_xor(ssum, 16);
        ssum += __shfl_xor(ssum, 32);
        lrun += ssum;

        // --- PV: O^T[e][q] += mfma(V~, P~); sigma-permute makes pc the exact B-fragment
        __builtin_amdgcn_s_setprio(1);
        #pragma unroll
        for (int s = 0; s < 2; ++s) {
            short8 pf = mk8(pc[4 * s], pc[4 * s + 1], pc[4 * s + 2], pc[4 * s + 3]);
            #pragma unroll
            for (int et = 0; et < 16; ++et) {
                short8 vf = *(const short8*)(VB + (16 * et + l15) * 128 + (((4 * s + G) ^ (l15 & 7)) * 16));
                oacc[et] = __builtin_amdgcn_mfma_f32_16x16x32_bf16(vf, pf, oacc[et], 0, 0, 0);
            }
        }
        __builtin_amdgcn_s_setprio(0);

        asm volatile("s_waitcnt lgkmcnt(0)" ::: "memory");
        __builtin_amdgcn_s_barrier();
        if (ch < 6) {
            STAGE(ch + 2, ch & 1)
            asm volatile("s_waitcnt vmcnt(8)" ::: "memory");
        } else if (ch == 6) {
            asm volatile("s_waitcnt vmcnt(0)" ::: "memory");
        }
        __builtin_amdgcn_s_barrier();
    }

    // --- epilogue (wave-local): 1/l, gelu, pack h fragments in-register
    float linv = 1.f / lrun;
    unsigned hc[32];
    #pragma unroll
    for (int et = 0; et < 16; ++et) {
        f32x4 xv = oacc[et] * linv;
        hc[2 * et]     = pkbf(gelu_t(xv[0]), gelu_t(xv[1]));
        hc[2 * et + 1] = pkbf(gelu_t(xv[2]), gelu_t(xv[3]));
    }
    float ym = fmaskL[128 + qh * 128 + wv * 16 + l15];

    // --- projection: y[o][s] = Wo~ . h~ + bo, Wo LDS-staged through K dbuf
    const unsigned short* wsrcp[4];
    #pragma unroll
    for (int i = 0; i < 4; ++i) {
        int wrow = wv * 8 + i * 2 + (lane >> 5);
        wsrcp[i] = Wo_b + (long)wrow * 256 + (((lane & 31) ^ (wrow & 7)) * 8);
    }
#define WSTAGE(ST, BUF) {                                                     \
        char* wl = SH + (BUF) * 32768 + wv * 4096;                            \
        _Pragma("unroll")                                                     \
        for (int i = 0; i < 4; ++i) gll16(wsrcp[i] + (ST) * 16384, wl + i * 1024); \
    }

    WSTAGE(0, 0)
    WSTAGE(1, 1)
    asm volatile("s_waitcnt vmcnt(4)" ::: "memory");
    __builtin_amdgcn_s_barrier();

    for (int step = 0; step < 8; ++step) {
        const char* WB = SH + (step & 1) * 32768;
        __builtin_amdgcn_s_setprio(1);
        #pragma unroll
        for (int otl = 0; otl < 4; ++otl) {
            f32x4 pacc = {};
            #pragma unroll
            for (int s = 0; s < 8; ++s) {
                short8 wf = *(const short8*)(WB + (16 * otl + l15) * 512 + (((4 * s + G) ^ (l15 & 7)) * 16));
                short8 hs = mk8(hc[4 * s], hc[4 * s + 1], hc[4 * s + 2], hc[4 * s + 3]);
                pacc = __builtin_amdgcn_mfma_f32_16x16x32_bf16(wf, hs, pacc, 0, 0, 0);
            }
            int o0 = step * 64 + 16 * otl + 4 * G;
            f32x4 bo4 = *(const f32x4*)&boL[o0];
            #pragma unroll
            for (int r = 0; r < 4; ++r)
                y[((long)b * Cc + o0 + r) * Ss + sqw + l15] = (pacc[r] + bo4[r]) * ym;
        }
        __builtin_amdgcn_s_setprio(0);
        asm volatile("s_waitcnt lgkmcnt(0)" ::: "memory");
        __builtin_amdgcn_s_barrier();
        if (step < 6) {
            WSTAGE(step + 2, step & 1)
            asm volatile("s_waitcnt vmcnt(4)" ::: "memory");
        } else if (step == 6) {
            asm volatile("s_waitcnt vmcnt(0)" ::: "memory");
        }
        __builtin_amdgcn_s_barrier();
    }
#undef STAGE
#undef WSTAGE
}

extern "C" void kernel_launch(void* const* d_in, const int* in_sizes, int n_in,
                              void* d_out, int out_size, void* d_ws, size_t ws_size,
                              hipStream_t stream)
{
    const float* x1   = (const float*)d_in[0];
    const float* mask = (const float*)d_in[1];
    const float* Wq   = (const float*)d_in[2];
    const float* bq   = (const float*)d_in[3];
    const float* Wk   = (const float*)d_in[4];
    const float* bk   = (const float*)d_in[5];
    const float* Wv   = (const float*)d_in[6];
    const float* bv   = (const float*)d_in[7];
    const float* Wo   = (const float*)d_in[8];
    const float* bo   = (const float*)d_in[9];
    float* y = (float*)d_out;

    // ws layout (bf16):
    // Wqkv_b 786432 | Wo_b 262144 | xT 8388608 | qT 16777216 | kTp 17301504 | vp 17301504
    if (ws_size < 60817408u) return;
    char* w = (char*)d_ws;
    unsigned short* Wqkv_b = (unsigned short*)(w);
    unsigned short* Wo_b   = (unsigned short*)(w + 786432);
    unsigned short* xT     = (unsigned short*)(w + 1048576);
    unsigned short* qT     = (unsigned short*)(w + 9437184);
    unsigned short* kTp    = (unsigned short*)(w + 26214400);
    unsigned short* vp     = (unsigned short*)(w + 43515904);

    kconv_w<<<1536, 256, 0, stream>>>(Wq, Wk, Wv, Wo, Wqkv_b, Wo_b);
    kzero<<<256, 256, 0, stream>>>(kTp, vp);
    for (int b = 0; b < 4; ++b) {
        ktr_x<<<1024, 256, 0, stream>>>(x1 + (long)b * Cc * Ss, xT);
        kqkv<<<384, 256, 0, stream>>>(xT, Wqkv_b, bq, bk, bv, qT, kTp, vp, b);
    }
    kattn<<<256, 512, 0, stream>>>(qT, kTp, vp, Wo_b, mask, bo, y);
}

// Round 5
// 155.506 us; speedup vs baseline: 2.1605x; 1.0017x over previous
//
#include <hip/hip_runtime.h>
#include <hip/hip_bf16.h>

typedef __attribute__((ext_vector_type(8))) short short8;
typedef __attribute__((ext_vector_type(4))) float f32x4;
typedef __attribute__((ext_vector_type(4))) int int4v;

#define DI __device__ __forceinline__

constexpr int Bq = 4, Cc = 512, Ss = 8192, Ee = 256;
constexpr int SP = 8448;   // padded s extent (128 + 8192 + 128)

DI unsigned short f2bf(float f) {
    unsigned int u = __float_as_uint(f);
    unsigned int r = u + 0x7fffu + ((u >> 16) & 1u);
    return (unsigned short)(r >> 16);
}

union U16x8 { int4v v; unsigned short u[8]; };

DI void gll16(const void* g, void* l) {
    __builtin_amdgcn_global_load_lds(
        (const __attribute__((address_space(1))) unsigned int*)g,
        (__attribute__((address_space(3))) unsigned int*)l, 16, 0, 0);
}

DI unsigned pkbf(float lo, float hi) {
    unsigned r;
    asm("v_cvt_pk_bf16_f32 %0, %1, %2" : "=v"(r) : "v"(lo), "v"(hi));
    return r;
}

DI short8 mk8(unsigned a, unsigned b, unsigned c, unsigned d) {
    int4v v; v[0] = (int)a; v[1] = (int)b; v[2] = (int)c; v[3] = (int)d;
    union { int4v i; short8 s; } U; U.i = v; return U.s;
}

DI f32x4 max4(f32x4 a, f32x4 b) {
    f32x4 r;
    r[0] = fmaxf(a[0], b[0]); r[1] = fmaxf(a[1], b[1]);
    r[2] = fmaxf(a[2], b[2]); r[3] = fmaxf(a[3], b[3]);
    return r;
}

DI float gelu_t(float x) {
    float x2 = x * x;
    float z = x * (0.7978845608f + 0.0356774081f * x2);
    float az = fabsf(z);
    float e = __expf(-2.f * az);
    float th = (1.f - e) / (1.f + e);
    th = (z < 0.f) ? -th : th;
    return 0.5f * x * (1.f + th);
}

// sigma on 5-bit index k = [G1 G0 j2 j1 j0] -> [j2 G1 G0 j1 j0]; sigma^3 = id
DI int SIG(int k)  { return ((k & 4) << 2) | ((k & 24) >> 1) | (k & 3); }
DI int SIG2(int k) { return SIG(SIG(k)); }

// ---------- convert weights to bf16: Wqkv [768][512], Wo [512][256] (Wo sigma-permuted cols) ----------
__global__ __launch_bounds__(256) void kconv_w(
    const float* __restrict__ Wq, const float* __restrict__ Wk, const float* __restrict__ Wv,
    const float* __restrict__ Wo, unsigned short* __restrict__ Wqkv_b, unsigned short* __restrict__ Wo_b)
{
    int i = blockIdx.x * 256 + threadIdx.x;
    if (i < 768 * 512) {
        int m = i >> 9, c = i & 511;
        const float* src = (m < 256) ? Wq : ((m < 512) ? Wk : Wv);
        Wqkv_b[i] = f2bf(src[(m & 255) * 512 + c]);
    }
    if (i < 512 * 256) {
        int kap = i & 255;
        int src = (i & ~255) | (kap & ~31) | SIG(kap & 31);
        Wo_b[i] = f2bf(Wo[src]);
    }
}

// ---------- zero pads of kTp (rows) and vp (cols) ----------
__global__ __launch_bounds__(256) void kzero(unsigned short* __restrict__ kTp, unsigned short* __restrict__ vp)
{
    int i = blockIdx.x * 256 + threadIdx.x;
    int4v z = {0, 0, 0, 0};
    if (i < 32768) {
        int b = i >> 13, r = i & 8191;
        int side = r >> 12, off = r & 4095;
        *(int4v*)(kTp + (long)b * SP * 256 + (long)(side ? 8320 : 0) * 256 + off * 8) = z;
    } else {
        int j = i - 32768;
        int b = j >> 13, r = j & 8191;
        int row = r >> 5, side = (r >> 4) & 1, sc = r & 15;
        *(int4v*)(vp + ((long)b * 256 + row) * SP + side * 8320 + sc * 8) = z;
    }
}

// ---------- transpose x1[b] (C,S) f32 -> xT (S,C) bf16 ----------
__global__ __launch_bounds__(256) void ktr_x(const float* __restrict__ x1b, unsigned short* __restrict__ xT)
{
    __shared__ unsigned short tile[64][72];
    int t = threadIdx.x;
    int bs = blockIdx.x & 127, bc = blockIdx.x >> 7;
    int s0 = bs * 64, c0 = bc * 64;
    int cl = t >> 4, sl = (t & 15) * 4;
    for (int it = 0; it < 4; ++it) {
        int c = cl + it * 16;
        float4 vv = *(const float4*)(x1b + (long)(c0 + c) * Ss + s0 + sl);
        tile[c][sl + 0] = f2bf(vv.x);
        tile[c][sl + 1] = f2bf(vv.y);
        tile[c][sl + 2] = f2bf(vv.z);
        tile[c][sl + 3] = f2bf(vv.w);
    }
    __syncthreads();
    int s_loc = t >> 2, cseg = (t & 3) * 16;
    for (int half = 0; half < 2; ++half) {
        U16x8 u;
        for (int j = 0; j < 8; ++j) u.u[j] = tile[cseg + half * 8 + j][s_loc];
        *(int4v*)(xT + (long)(s0 + s_loc) * Cc + c0 + cseg + half * 8) = u.v;
    }
}

// ---------- QKV GEMM (per batch): q,k -> [s][e], v -> [e][s] with sigma-permuted cols ----------
__global__ __launch_bounds__(256) void kqkv(
    const unsigned short* __restrict__ xT, const unsigned short* __restrict__ Wqkv,
    const float* __restrict__ bq, const float* __restrict__ bk, const float* __restrict__ bv,
    unsigned short* __restrict__ qT, unsigned short* __restrict__ kTp, unsigned short* __restrict__ vp,
    int b)
{
    __shared__ int4v As[1024], Bs[1024];
    int wg = blockIdx.x;
    int type = wg >> 7, id = wg & 127;     // 0=q 1=k 2=v
    const unsigned short *A, *Bt; unsigned short* Op;
    long opitch; const float* bias; bool biasRow;
    if (type < 2) {
        int mt = id >> 1, nt = id & 1;
        A  = xT + (long)(mt * 128) * 512;
        Bt = Wqkv + (long)(type * 256 + nt * 128) * 512;
        if (type == 0)
            Op = qT + (long)b * Ss * Ee + (long)(mt * 128) * Ee + nt * 128;
        else
            Op = kTp + (long)b * SP * Ee + (long)(128 + mt * 128) * Ee + nt * 128;
        opitch = Ee;
        bias = (type ? bk : bq) + nt * 128;
        biasRow = false;
    } else {
        int mt = id >> 6, nt = id & 63;
        A  = Wqkv + (long)(512 + mt * 128) * 512;
        Bt = xT + (long)(nt * 128) * 512;
        Op = vp + (long)b * Ee * SP + (long)(mt * 128) * SP + 128 + nt * 128;
        opitch = SP;
        bias = bv + mt * 128;
        biasRow = true;
    }
    int t = threadIdx.x, lane = t & 63, wv = t >> 6;
    int wr = (wv >> 1) * 64, wc = (wv & 1) * 64;
    f32x4 acc[4][4] = {};
    for (int kk = 0; kk < 8; ++kk) {
        __syncthreads();
        for (int i = 0; i < 4; ++i) {
            int seg = t + 256 * i;
            int row = seg >> 3, cs = seg & 7;
            int4v va = *(const int4v*)(A  + (long)row * 512 + kk * 64 + cs * 8);
            int4v vb = *(const int4v*)(Bt + (long)row * 512 + kk * 64 + cs * 8);
            As[row * 8 + (cs ^ (row & 7))] = va;
            Bs[row * 8 + (cs ^ (row & 7))] = vb;
        }
        __syncthreads();
        for (int ks = 0; ks < 2; ++ks) {
            int csk = ks * 4 + (lane >> 4);
            short8 af[4], bfr[4];
            #pragma unroll
            for (int mi = 0; mi < 4; ++mi) {
                int m = wr + mi * 16 + (lane & 15);
                af[mi] = *(const short8*)&As[m * 8 + (csk ^ (m & 7))];
            }
            #pragma unroll
            for (int ni = 0; ni < 4; ++ni) {
                int nn = wc + ni * 16 + (lane & 15);
                bfr[ni] = *(const short8*)&Bs[nn * 8 + (csk ^ (nn & 7))];
            }
            #pragma unroll
            for (int mi = 0; mi < 4; ++mi)
                #pragma unroll
                for (int ni = 0; ni < 4; ++ni)
                    acc[mi][ni] = __builtin_amdgcn_mfma_f32_16x16x32_bf16(af[mi], bfr[ni], acc[mi][ni], 0, 0, 0);
        }
    }
    for (int mi = 0; mi < 4; ++mi)
        for (int ni = 0; ni < 4; ++ni) {
            int mrow = wr + mi * 16 + ((lane >> 4) * 4);
            int ncol = wc + ni * 16 + (lane & 15);
            int nc2 = biasRow ? ((ncol & ~31) | SIG2(ncol & 31)) : ncol;
            for (int r = 0; r < 4; ++r) {
                float bval = biasRow ? bias[mrow + r] : bias[ncol];
                Op[(long)(mrow + r) * opitch + nc2] = f2bf(acc[mi][ni][r] + bval);
            }
        }
}

// ---------- fused attention + gelu + output projection ----------
// grid 256 = (b,n,qhalf) XCD-paired; 8 waves x 16 q rows; swapped QK^T -> in-lane softmax;
// sigma-permuted V/Wo -> zero-shuffle P/h fragments; LDS-staged Wo projection.
__global__ __launch_bounds__(512, 1) void kattn(
    const unsigned short* __restrict__ qT, const unsigned short* __restrict__ kTp,
    const unsigned short* __restrict__ vp,  const unsigned short* __restrict__ Wo_b,
    const float* __restrict__ mask, const float* __restrict__ bo,
    float* __restrict__ y)
{
    // LDS: K dbuf 2x32KB (also Wo dbuf in proj) | V dbuf 2x32KB | fmask 2KB | lmask 2KB | bo 2KB
    __shared__ __align__(16) char SH[137216];
    float* fmaskL = (float*)(SH + 131072);
    float* lmaskL = (float*)(SH + 133120);
    float* boL    = (float*)(SH + 135168);

    int t = threadIdx.x, lane = t & 63, wv = t >> 6;   // wv in [0,8)
    int G = lane >> 4, l15 = lane & 15;

    // XCD swizzle: pair (qh=0,1) of same (b,n) onto same XCD (assumes phys%8 = XCD)
    int phys = blockIdx.x;
    int xx = phys & 7, kk2 = phys >> 3;
    int L = ((xx + 8 * (kk2 >> 1)) << 1) | (kk2 & 1);
    int qh = L & 1, n = (L >> 1) & 31, b = L >> 6;
    int sqw = n * 256 + qh * 128 + wv * 16;

    // --- Q fragments direct from global (B-operand: rows = q, k = e)
    short8 qfrag[8];
    #pragma unroll
    for (int s = 0; s < 8; ++s)
        qfrag[s] = *(const short8*)(qT + ((long)b * Ss + sqw + l15) * 256 + 32 * s + 8 * G);

    // --- window masks + bias
    {
        int i = t;
        int sw = n * 256 - 128 + i;
        float f = 0.f;
        if (i != 511 && sw >= 0 && sw < Ss) f = mask[(long)b * Ss + sw];
        fmaskL[i] = f;
        lmaskL[i] = __logf(f + 1e-6f);
    }
    if (t < 128) ((float4*)boL)[t] = ((const float4*)bo)[t];

    // --- staging source pointers (pre-swizzled global, linear LDS dest)
    const unsigned short* ksrcp[4];
    const unsigned short* vsrcp[4];
    #pragma unroll
    for (int i = 0; i < 4; ++i) {
        int krow = wv * 8 + i * 2 + (lane >> 5);
        ksrcp[i] = kTp + ((long)b * SP + n * 256 + krow) * 256 + (((lane & 31) ^ (krow & 7)) * 8);
        int erow = wv * 32 + i * 8 + (lane >> 3);
        vsrcp[i] = vp + ((long)b * 256 + erow) * SP + n * 256 + (((lane & 7) ^ ((lane >> 3) & 7)) * 8);
    }

#define STAGE(CH, BUF) {                                                      \
        char* kl = SH + (BUF) * 32768 + wv * 4096;                            \
        char* vl = SH + 65536 + (BUF) * 32768 + wv * 4096;                    \
        _Pragma("unroll")                                                     \
        for (int i = 0; i < 4; ++i) gll16(ksrcp[i] + (long)(CH) * 16384, kl + i * 1024); \
        _Pragma("unroll")                                                     \
        for (int i = 0; i < 4; ++i) gll16(vsrcp[i] + (CH) * 64, vl + i * 1024);          \
    }

    STAGE(0, 0)
    STAGE(1, 1)
    asm volatile("s_waitcnt vmcnt(8) lgkmcnt(0)" ::: "memory");
    __builtin_amdgcn_s_barrier();

    float mrun = -1e30f, lrun = 0.f;
    f32x4 oacc[16] = {};

    for (int ch = 0; ch < 8; ++ch) {
        const char* KB = SH + (ch & 1) * 32768;
        const char* VB = SH + 65536 + (ch & 1) * 32768;

        // --- energy: E^T[w][q] = mfma(K, Q); 64 keys = 4 w-tiles
        f32x4 eacc[4] = {};
        __builtin_amdgcn_s_setprio(1);
        #pragma unroll
        for (int s = 0; s < 8; ++s) {
            short8 kf[4];
            #pragma unroll
            for (int tt = 0; tt < 4; ++tt)
                kf[tt] = *(const short8*)(KB + (16 * tt + l15) * 512 + (((4 * s + G) ^ (l15 & 7)) * 16));
            #pragma unroll
            for (int tt = 0; tt < 4; ++tt)
                eacc[tt] = __builtin_amdgcn_mfma_f32_16x16x32_bf16(kf[tt], qfrag[s], eacc[tt], 0, 0, 0);
        }
        __builtin_amdgcn_s_setprio(0);

        int w0 = ch * 64;
        f32x4 lm[4], fm[4];
        #pragma unroll
        for (int tt = 0; tt < 4; ++tt) {
            lm[tt] = *(const f32x4*)&lmaskL[w0 + 16 * tt + 4 * G];
            fm[tt] = *(const f32x4*)&fmaskL[w0 + 16 * tt + 4 * G];
        }

        // --- in-lane online softmax (q = l15)
        f32x4 ev[4];
        f32x4 m4;
        #pragma unroll
        for (int tt = 0; tt < 4; ++tt) {
            ev[tt] = eacc[tt] * 0.0625f + lm[tt];
            m4 = tt ? max4(m4, ev[tt]) : ev[tt];
        }
        float cm = fmaxf(fmaxf(m4[0], m4[1]), fmaxf(m4[2], m4[3]));
        cm = fmaxf(cm, __shfl_xor(cm, 16));
        cm = fmaxf(cm, __shfl_xor(cm, 32));
        if (__any(cm > mrun + 8.f)) {
            float mn = fmaxf(mrun, cm);
            float sc = __expf(mrun - mn);
            mrun = mn; lrun *= sc;
            #pragma unroll
            for (int et = 0; et < 16; ++et) oacc[et] *= sc;
        }

        unsigned pc[8];
        float ssum = 0.f;
        #pragma unroll
        for (int tt = 0; tt < 4; ++tt) {
            f32x4 p;
            p[0] = __expf(ev[tt][0] - mrun);
            p[1] = __expf(ev[tt][1] - mrun);
            p[2] = __expf(ev[tt][2] - mrun);
            p[3] = __expf(ev[tt][3] - mrun);
            ssum += (p[0] + p[1]) + (p[2] + p[3]);
            f32x4 pf = p * fm[tt];
            pc[2 * tt]     = pkbf(pf[0], pf[1]);
            pc[2 * tt + 1] = pkbf(pf[2], pf[3]);
        }
        ssum += __shfl_xor(ssum, 16);
        ssum += __shfl_xor(ssum, 32);
        lrun += ssum;

        // --- PV: O^T[e][q] += mfma(V~, P~); sigma-permute makes pc the exact B-fragment
        __builtin_amdgcn_s_setprio(1);
        #pragma unroll
        for (int s = 0; s < 2; ++s) {
            short8 pf = mk8(pc[4 * s], pc[4 * s + 1], pc[4 * s + 2], pc[4 * s + 3]);
            #pragma unroll
            for (int et = 0; et < 16; ++et) {
                short8 vf = *(const short8*)(VB + (16 * et + l15) * 128 + (((4 * s + G) ^ (l15 & 7)) * 16));
                oacc[et] = __builtin_amdgcn_mfma_f32_16x16x32_bf16(vf, pf, oacc[et], 0, 0, 0);
            }
        }
        __builtin_amdgcn_s_setprio(0);

        asm volatile("s_waitcnt lgkmcnt(0)" ::: "memory");
        __builtin_amdgcn_s_barrier();
        if (ch < 6) {
            STAGE(ch + 2, ch & 1)
            asm volatile("s_waitcnt vmcnt(8)" ::: "memory");
        } else if (ch == 6) {
            asm volatile("s_waitcnt vmcnt(0)" ::: "memory");
        }
        __builtin_amdgcn_s_barrier();
    }

    // --- epilogue (wave-local): 1/l, gelu, pack h fragments in-register
    float linv = 1.f / lrun;
    unsigned hc[32];
    #pragma unroll
    for (int et = 0; et < 16; ++et) {
        f32x4 xv = oacc[et] * linv;
        hc[2 * et]     = pkbf(gelu_t(xv[0]), gelu_t(xv[1]));
        hc[2 * et + 1] = pkbf(gelu_t(xv[2]), gelu_t(xv[3]));
    }
    float ym = fmaskL[128 + qh * 128 + wv * 16 + l15];

    // --- projection: y[o][s] = Wo~ . h~ + bo, Wo LDS-staged through K dbuf
    const unsigned short* wsrcp[4];
    #pragma unroll
    for (int i = 0; i < 4; ++i) {
        int wrow = wv * 8 + i * 2 + (lane >> 5);
        wsrcp[i] = Wo_b + (long)wrow * 256 + (((lane & 31) ^ (wrow & 7)) * 8);
    }
#define WSTAGE(ST, BUF) {                                                     \
        char* wl = SH + (BUF) * 32768 + wv * 4096;                            \
        _Pragma("unroll")                                                     \
        for (int i = 0; i < 4; ++i) gll16(wsrcp[i] + (ST) * 16384, wl + i * 1024); \
    }

    WSTAGE(0, 0)
    WSTAGE(1, 1)
    asm volatile("s_waitcnt vmcnt(4)" ::: "memory");
    __builtin_amdgcn_s_barrier();

    for (int step = 0; step < 8; ++step) {
        const char* WB = SH + (step & 1) * 32768;
        __builtin_amdgcn_s_setprio(1);
        #pragma unroll
        for (int otl = 0; otl < 4; ++otl) {
            f32x4 pacc = {};
            #pragma unroll
            for (int s = 0; s < 8; ++s) {
                short8 wf = *(const short8*)(WB + (16 * otl + l15) * 512 + (((4 * s + G) ^ (l15 & 7)) * 16));
                short8 hs = mk8(hc[4 * s], hc[4 * s + 1], hc[4 * s + 2], hc[4 * s + 3]);
                pacc = __builtin_amdgcn_mfma_f32_16x16x32_bf16(wf, hs, pacc, 0, 0, 0);
            }
            int o0 = step * 64 + 16 * otl + 4 * G;
            f32x4 bo4 = *(const f32x4*)&boL[o0];
            #pragma unroll
            for (int r = 0; r < 4; ++r)
                y[((long)b * Cc + o0 + r) * Ss + sqw + l15] = (pacc[r] + bo4[r]) * ym;
        }
        __builtin_amdgcn_s_setprio(0);
        asm volatile("s_waitcnt lgkmcnt(0)" ::: "memory");
        __builtin_amdgcn_s_barrier();
        if (step < 6) {
            WSTAGE(step + 2, step & 1)
            asm volatile("s_waitcnt vmcnt(4)" ::: "memory");
        } else if (step == 6) {
            asm volatile("s_waitcnt vmcnt(0)" ::: "memory");
        }
        __builtin_amdgcn_s_barrier();
    }
#undef STAGE
#undef WSTAGE
}

extern "C" void kernel_launch(void* const* d_in, const int* in_sizes, int n_in,
                              void* d_out, int out_size, void* d_ws, size_t ws_size,
                              hipStream_t stream)
{
    const float* x1   = (const float*)d_in[0];
    const float* mask = (const float*)d_in[1];
    const float* Wq   = (const float*)d_in[2];
    const float* bq   = (const float*)d_in[3];
    const float* Wk   = (const float*)d_in[4];
    const float* bk   = (const float*)d_in[5];
    const float* Wv   = (const float*)d_in[6];
    const float* bv   = (const float*)d_in[7];
    const float* Wo   = (const float*)d_in[8];
    const float* bo   = (const float*)d_in[9];
    float* y = (float*)d_out;

    // ws layout (bf16):
    // Wqkv_b 786432 | Wo_b 262144 | xT 8388608 | qT 16777216 | kTp 17301504 | vp 17301504
    if (ws_size < 60817408u) return;
    char* w = (char*)d_ws;
    unsigned short* Wqkv_b = (unsigned short*)(w);
    unsigned short* Wo_b   = (unsigned short*)(w + 786432);
    unsigned short* xT     = (unsigned short*)(w + 1048576);
    unsigned short* qT     = (unsigned short*)(w + 9437184);
    unsigned short* kTp    = (unsigned short*)(w + 26214400);
    unsigned short* vp     = (unsigned short*)(w + 43515904);

    kconv_w<<<1536, 256, 0, stream>>>(Wq, Wk, Wv, Wo, Wqkv_b, Wo_b);
    kzero<<<256, 256, 0, stream>>>(kTp, vp);
    for (int b = 0; b < 4; ++b) {
        ktr_x<<<1024, 256, 0, stream>>>(x1 + (long)b * Cc * Ss, xT);
        kqkv<<<384, 256, 0, stream>>>(xT, Wqkv_b, bq, bk, bv, qT, kTp, vp, b);
    }
    kattn<<<256, 512, 0, stream>>>(qT, kTp, vp, Wo_b, mask, bo, y);
}

// Round 6
// 118.943 us; speedup vs baseline: 2.8246x; 1.3074x over previous
//
#include <hip/hip_runtime.h>
#include <hip/hip_bf16.h>

typedef __attribute__((ext_vector_type(8))) short short8;
typedef __attribute__((ext_vector_type(4))) float f32x4;
typedef __attribute__((ext_vector_type(4))) int int4v;

#define DI __device__ __forceinline__

constexpr int Bq = 4, Cc = 512, Ss = 8192, Ee = 256;
constexpr int SP = 8448;   // padded s extent (128 + 8192 + 128)
constexpr long XSLAB = 4194304;  // xT slab elems (8192*512)

DI unsigned short f2bf(float f) {
    unsigned int u = __float_as_uint(f);
    unsigned int r = u + 0x7fffu + ((u >> 16) & 1u);
    return (unsigned short)(r >> 16);
}

union U16x8 { int4v v; unsigned short u[8]; };

DI void gll16(const void* g, void* l) {
    __builtin_amdgcn_global_load_lds(
        (const __attribute__((address_space(1))) unsigned int*)g,
        (__attribute__((address_space(3))) unsigned int*)l, 16, 0, 0);
}

DI unsigned pkbf(float lo, float hi) {
    unsigned r;
    asm("v_cvt_pk_bf16_f32 %0, %1, %2" : "=v"(r) : "v"(lo), "v"(hi));
    return r;
}

DI short8 mk8(unsigned a, unsigned b, unsigned c, unsigned d) {
    int4v v; v[0] = (int)a; v[1] = (int)b; v[2] = (int)c; v[3] = (int)d;
    union { int4v i; short8 s; } U; U.i = v; return U.s;
}

DI f32x4 max4(f32x4 a, f32x4 b) {
    f32x4 r;
    r[0] = fmaxf(a[0], b[0]); r[1] = fmaxf(a[1], b[1]);
    r[2] = fmaxf(a[2], b[2]); r[3] = fmaxf(a[3], b[3]);
    return r;
}

DI float gelu_t(float x) {
    float x2 = x * x;
    float z = x * (0.7978845608f + 0.0356774081f * x2);
    float az = fabsf(z);
    float e = __expf(-2.f * az);
    float th = (1.f - e) / (1.f + e);
    th = (z < 0.f) ? -th : th;
    return 0.5f * x * (1.f + th);
}

// sigma on 5-bit index k = [G1 G0 j2 j1 j0] -> [j2 G1 G0 j1 j0]; sigma^3 = id
DI int SIG(int k)  { return ((k & 4) << 2) | ((k & 24) >> 1) | (k & 3); }
DI int SIG2(int k) { return SIG(SIG(k)); }

// ---------- merged prep: weights->bf16 (Wo sigma-permuted) + zero pads of kTp/vp ----------
__global__ __launch_bounds__(256) void kprep(
    const float* __restrict__ Wq, const float* __restrict__ Wk, const float* __restrict__ Wv,
    const float* __restrict__ Wo, unsigned short* __restrict__ Wqkv_b, unsigned short* __restrict__ Wo_b,
    unsigned short* __restrict__ kTp, unsigned short* __restrict__ vp)
{
    int blk = blockIdx.x, t = threadIdx.x;
    if (blk < 1536) {
        int i = blk * 256 + t;
        if (i < 768 * 512) {
            int m = i >> 9, c = i & 511;
            const float* src = (m < 256) ? Wq : ((m < 512) ? Wk : Wv);
            Wqkv_b[i] = f2bf(src[(m & 255) * 512 + c]);
        }
        if (i < 512 * 256) {
            int kap = i & 255;
            int src = (i & ~255) | (kap & ~31) | SIG(kap & 31);
            Wo_b[i] = f2bf(Wo[src]);
        }
    } else {
        int i = (blk - 1536) * 256 + t;   // 0..65535
        int4v z = {0, 0, 0, 0};
        if (i < 32768) {
            int b = i >> 13, r = i & 8191;
            int side = r >> 12, off = r & 4095;
            *(int4v*)(kTp + (long)b * SP * 256 + (long)(side ? 8320 : 0) * 256 + off * 8) = z;
        } else {
            int j = i - 32768;
            int b = j >> 13, r = j & 8191;
            int row = r >> 5, side = (r >> 4) & 1, sc = r & 15;
            *(int4v*)(vp + ((long)b * 256 + row) * SP + side * 8320 + sc * 8) = z;
        }
    }
}

// ---------- transpose x1[b] (C,S) f32 -> xT (S,C) bf16; blockIdx.y = batch within group ----------
__global__ __launch_bounds__(256) void ktr_x(const float* __restrict__ x1g, unsigned short* __restrict__ xT4)
{
    const float* x1b = x1g + (long)blockIdx.y * Cc * Ss;
    unsigned short* xT = xT4 + (long)blockIdx.y * XSLAB;
    __shared__ unsigned short tile[64][72];
    int t = threadIdx.x;
    int bs = blockIdx.x & 127, bc = blockIdx.x >> 7;
    int s0 = bs * 64, c0 = bc * 64;
    int cl = t >> 4, sl = (t & 15) * 4;
    for (int it = 0; it < 4; ++it) {
        int c = cl + it * 16;
        float4 vv = *(const float4*)(x1b + (long)(c0 + c) * Ss + s0 + sl);
        tile[c][sl + 0] = f2bf(vv.x);
        tile[c][sl + 1] = f2bf(vv.y);
        tile[c][sl + 2] = f2bf(vv.z);
        tile[c][sl + 3] = f2bf(vv.w);
    }
    __syncthreads();
    int s_loc = t >> 2, cseg = (t & 3) * 16;
    for (int half = 0; half < 2; ++half) {
        U16x8 u;
        for (int j = 0; j < 8; ++j) u.u[j] = tile[cseg + half * 8 + j][s_loc];
        *(int4v*)(xT + (long)(s0 + s_loc) * Cc + c0 + cseg + half * 8) = u.v;
    }
}

// ---------- QKV GEMM: q,k -> [s][e], v -> [e][s] sigma-permuted cols; gll16 staging ----------
// blockIdx.y = batch within group (b = b0 + y); xT slab per y.
__global__ __launch_bounds__(256) void kqkv(
    const unsigned short* __restrict__ xT4, const unsigned short* __restrict__ Wqkv,
    const float* __restrict__ bq, const float* __restrict__ bk, const float* __restrict__ bv,
    unsigned short* __restrict__ qT, unsigned short* __restrict__ kTp, unsigned short* __restrict__ vp,
    int b0)
{
    __shared__ int4v As[1024], Bs[1024];
    int b = b0 + blockIdx.y;
    const unsigned short* xT = xT4 + (long)blockIdx.y * XSLAB;
    int wg = blockIdx.x;
    int type = wg >> 7, id = wg & 127;     // 0=q 1=k 2=v
    const unsigned short *A, *Bt; unsigned short* Op;
    long opitch; const float* bias; bool biasRow;
    if (type < 2) {
        int mt = id >> 1, nt = id & 1;
        A  = xT + (long)(mt * 128) * 512;
        Bt = Wqkv + (long)(type * 256 + nt * 128) * 512;
        if (type == 0)
            Op = qT + (long)b * Ss * Ee + (long)(mt * 128) * Ee + nt * 128;
        else
            Op = kTp + (long)b * SP * Ee + (long)(128 + mt * 128) * Ee + nt * 128;
        opitch = Ee;
        bias = (type ? bk : bq) + nt * 128;
        biasRow = false;
    } else {
        int mt = id >> 6, nt = id & 63;
        A  = Wqkv + (long)(512 + mt * 128) * 512;
        Bt = xT + (long)(nt * 128) * 512;
        Op = vp + (long)b * Ee * SP + (long)(mt * 128) * SP + 128 + nt * 128;
        opitch = SP;
        bias = bv + mt * 128;
        biasRow = true;
    }
    int t = threadIdx.x, lane = t & 63, wv = t >> 6;
    int wr = (wv >> 1) * 64, wc = (wv & 1) * 64;

    // gll16: pre-swizzled global source offsets (elems); linear LDS dest
    int soff[4];
    #pragma unroll
    for (int i = 0; i < 4; ++i) {
        int seg = t + 256 * i, row = seg >> 3, cs = seg & 7;
        soff[i] = row * 512 + ((cs ^ (row & 7)) * 8);
    }
    char* adst = (char*)As + wv * 1024;
    char* bdst = (char*)Bs + wv * 1024;

    f32x4 acc[4][4] = {};
    for (int kk = 0; kk < 8; ++kk) {
        #pragma unroll
        for (int i = 0; i < 4; ++i) {
            gll16(A  + soff[i] + kk * 64, adst + i * 4096);
            gll16(Bt + soff[i] + kk * 64, bdst + i * 4096);
        }
        asm volatile("s_waitcnt vmcnt(0)" ::: "memory");
        __syncthreads();
        for (int ks = 0; ks < 2; ++ks) {
            int csk = ks * 4 + (lane >> 4);
            short8 af[4], bfr[4];
            #pragma unroll
            for (int mi = 0; mi < 4; ++mi) {
                int m = wr + mi * 16 + (lane & 15);
                af[mi] = *(const short8*)&As[m * 8 + (csk ^ (m & 7))];
            }
            #pragma unroll
            for (int ni = 0; ni < 4; ++ni) {
                int nn = wc + ni * 16 + (lane & 15);
                bfr[ni] = *(const short8*)&Bs[nn * 8 + (csk ^ (nn & 7))];
            }
            #pragma unroll
            for (int mi = 0; mi < 4; ++mi)
                #pragma unroll
                for (int ni = 0; ni < 4; ++ni)
                    acc[mi][ni] = __builtin_amdgcn_mfma_f32_16x16x32_bf16(af[mi], bfr[ni], acc[mi][ni], 0, 0, 0);
        }
        __syncthreads();
    }
    for (int mi = 0; mi < 4; ++mi)
        for (int ni = 0; ni < 4; ++ni) {
            int mrow = wr + mi * 16 + ((lane >> 4) * 4);
            int ncol = wc + ni * 16 + (lane & 15);
            int nc2 = biasRow ? ((ncol & ~31) | SIG2(ncol & 31)) : ncol;
            for (int r = 0; r < 4; ++r) {
                float bval = biasRow ? bias[mrow + r] : bias[ncol];
                Op[(long)(mrow + r) * opitch + nc2] = f2bf(acc[mi][ni][r] + bval);
            }
        }
}

// ---------- fused attention + gelu + output projection (unchanged from r5) ----------
__global__ __launch_bounds__(512, 1) void kattn(
    const unsigned short* __restrict__ qT, const unsigned short* __restrict__ kTp,
    const unsigned short* __restrict__ vp,  const unsigned short* __restrict__ Wo_b,
    const float* __restrict__ mask, const float* __restrict__ bo,
    float* __restrict__ y)
{
    __shared__ __align__(16) char SH[137216];
    float* fmaskL = (float*)(SH + 131072);
    float* lmaskL = (float*)(SH + 133120);
    float* boL    = (float*)(SH + 135168);

    int t = threadIdx.x, lane = t & 63, wv = t >> 6;   // wv in [0,8)
    int G = lane >> 4, l15 = lane & 15;

    int phys = blockIdx.x;
    int xx = phys & 7, kk2 = phys >> 3;
    int L = ((xx + 8 * (kk2 >> 1)) << 1) | (kk2 & 1);
    int qh = L & 1, n = (L >> 1) & 31, b = L >> 6;
    int sqw = n * 256 + qh * 128 + wv * 16;

    short8 qfrag[8];
    #pragma unroll
    for (int s = 0; s < 8; ++s)
        qfrag[s] = *(const short8*)(qT + ((long)b * Ss + sqw + l15) * 256 + 32 * s + 8 * G);

    {
        int i = t;
        int sw = n * 256 - 128 + i;
        float f = 0.f;
        if (i != 511 && sw >= 0 && sw < Ss) f = mask[(long)b * Ss + sw];
        fmaskL[i] = f;
        lmaskL[i] = __logf(f + 1e-6f);
    }
    if (t < 128) ((float4*)boL)[t] = ((const float4*)bo)[t];

    const unsigned short* ksrcp[4];
    const unsigned short* vsrcp[4];
    #pragma unroll
    for (int i = 0; i < 4; ++i) {
        int krow = wv * 8 + i * 2 + (lane >> 5);
        ksrcp[i] = kTp + ((long)b * SP + n * 256 + krow) * 256 + (((lane & 31) ^ (krow & 7)) * 8);
        int erow = wv * 32 + i * 8 + (lane >> 3);
        vsrcp[i] = vp + ((long)b * 256 + erow) * SP + n * 256 + (((lane & 7) ^ ((lane >> 3) & 7)) * 8);
    }

#define STAGE(CH, BUF) {                                                      \
        char* kl = SH + (BUF) * 32768 + wv * 4096;                            \
        char* vl = SH + 65536 + (BUF) * 32768 + wv * 4096;                    \
        _Pragma("unroll")                                                     \
        for (int i = 0; i < 4; ++i) gll16(ksrcp[i] + (long)(CH) * 16384, kl + i * 1024); \
        _Pragma("unroll")                                                     \
        for (int i = 0; i < 4; ++i) gll16(vsrcp[i] + (CH) * 64, vl + i * 1024);          \
    }

    STAGE(0, 0)
    STAGE(1, 1)
    asm volatile("s_waitcnt vmcnt(8) lgkmcnt(0)" ::: "memory");
    __builtin_amdgcn_s_barrier();

    float mrun = -1e30f, lrun = 0.f;
    f32x4 oacc[16] = {};

    for (int ch = 0; ch < 8; ++ch) {
        const char* KB = SH + (ch & 1) * 32768;
        const char* VB = SH + 65536 + (ch & 1) * 32768;

        f32x4 eacc[4] = {};
        __builtin_amdgcn_s_setprio(1);
        #pragma unroll
        for (int s = 0; s < 8; ++s) {
            short8 kf[4];
            #pragma unroll
            for (int tt = 0; tt < 4; ++tt)
                kf[tt] = *(const short8*)(KB + (16 * tt + l15) * 512 + (((4 * s + G) ^ (l15 & 7)) * 16));
            #pragma unroll
            for (int tt = 0; tt < 4; ++tt)
                eacc[tt] = __builtin_amdgcn_mfma_f32_16x16x32_bf16(kf[tt], qfrag[s], eacc[tt], 0, 0, 0);
        }
        __builtin_amdgcn_s_setprio(0);

        int w0 = ch * 64;
        f32x4 lm[4], fm[4];
        #pragma unroll
        for (int tt = 0; tt < 4; ++tt) {
            lm[tt] = *(const f32x4*)&lmaskL[w0 + 16 * tt + 4 * G];
            fm[tt] = *(const f32x4*)&fmaskL[w0 + 16 * tt + 4 * G];
        }

        f32x4 ev[4];
        f32x4 m4;
        #pragma unroll
        for (int tt = 0; tt < 4; ++tt) {
            ev[tt] = eacc[tt] * 0.0625f + lm[tt];
            m4 = tt ? max4(m4, ev[tt]) : ev[tt];
        }
        float cm = fmaxf(fmaxf(m4[0], m4[1]), fmaxf(m4[2], m4[3]));
        cm = fmaxf(cm, __shfl_xor(cm, 16));
        cm = fmaxf(cm, __shfl_xor(cm, 32));
        if (__any(cm > mrun + 8.f)) {
            float mn = fmaxf(mrun, cm);
            float sc = __expf(mrun - mn);
            mrun = mn; lrun *= sc;
            #pragma unroll
            for (int et = 0; et < 16; ++et) oacc[et] *= sc;
        }

        unsigned pc[8];
        float ssum = 0.f;
        #pragma unroll
        for (int tt = 0; tt < 4; ++tt) {
            f32x4 p;
            p[0] = __expf(ev[tt][0] - mrun);
            p[1] = __expf(ev[tt][1] - mrun);
            p[2] = __expf(ev[tt][2] - mrun);
            p[3] = __expf(ev[tt][3] - mrun);
            ssum += (p[0] + p[1]) + (p[2] + p[3]);
            f32x4 pf = p * fm[tt];
            pc[2 * tt]     = pkbf(pf[0], pf[1]);
            pc[2 * tt + 1] = pkbf(pf[2], pf[3]);
        }
        ssum += __shfl_xor(ssum, 16);
        ssum += __shfl_xor(ssum, 32);
        lrun += ssum;

        __builtin_amdgcn_s_setprio(1);
        #pragma unroll
        for (int s = 0; s < 2; ++s) {
            short8 pf = mk8(pc[4 * s], pc[4 * s + 1], pc[4 * s + 2], pc[4 * s + 3]);
            #pragma unroll
            for (int et = 0; et < 16; ++et) {
                short8 vf = *(const short8*)(VB + (16 * et + l15) * 128 + (((4 * s + G) ^ (l15 & 7)) * 16));
                oacc[et] = __builtin_amdgcn_mfma_f32_16x16x32_bf16(vf, pf, oacc[et], 0, 0, 0);
            }
        }
        __builtin_amdgcn_s_setprio(0);

        asm volatile("s_waitcnt lgkmcnt(0)" ::: "memory");
        __builtin_amdgcn_s_barrier();
        if (ch < 6) {
            STAGE(ch + 2, ch & 1)
            asm volatile("s_waitcnt vmcnt(8)" ::: "memory");
        } else if (ch == 6) {
            asm volatile("s_waitcnt vmcnt(0)" ::: "memory");
        }
        __builtin_amdgcn_s_barrier();
    }

    float linv = 1.f / lrun;
    unsigned hc[32];
    #pragma unroll
    for (int et = 0; et < 16; ++et) {
        f32x4 xv = oacc[et] * linv;
        hc[2 * et]     = pkbf(gelu_t(xv[0]), gelu_t(xv[1]));
        hc[2 * et + 1] = pkbf(gelu_t(xv[2]), gelu_t(xv[3]));
    }
    float ym = fmaskL[128 + qh * 128 + wv * 16 + l15];

    const unsigned short* wsrcp[4];
    #pragma unroll
    for (int i = 0; i < 4; ++i) {
        int wrow = wv * 8 + i * 2 + (lane >> 5);
        wsrcp[i] = Wo_b + (long)wrow * 256 + (((lane & 31) ^ (wrow & 7)) * 8);
    }
#define WSTAGE(ST, BUF) {                                                     \
        char* wl = SH + (BUF) * 32768 + wv * 4096;                            \
        _Pragma("unroll")                                                     \
        for (int i = 0; i < 4; ++i) gll16(wsrcp[i] + (ST) * 16384, wl + i * 1024); \
    }

    WSTAGE(0, 0)
    WSTAGE(1, 1)
    asm volatile("s_waitcnt vmcnt(4)" ::: "memory");
    __builtin_amdgcn_s_barrier();

    for (int step = 0; step < 8; ++step) {
        const char* WB = SH + (step & 1) * 32768;
        __builtin_amdgcn_s_setprio(1);
        #pragma unroll
        for (int otl = 0; otl < 4; ++otl) {
            f32x4 pacc = {};
            #pragma unroll
            for (int s = 0; s < 8; ++s) {
                short8 wf = *(const short8*)(WB + (16 * otl + l15) * 512 + (((4 * s + G) ^ (l15 & 7)) * 16));
                short8 hs = mk8(hc[4 * s], hc[4 * s + 1], hc[4 * s + 2], hc[4 * s + 3]);
                pacc = __builtin_amdgcn_mfma_f32_16x16x32_bf16(wf, hs, pacc, 0, 0, 0);
            }
            int o0 = step * 64 + 16 * otl + 4 * G;
            f32x4 bo4 = *(const f32x4*)&boL[o0];
            #pragma unroll
            for (int r = 0; r < 4; ++r)
                y[((long)b * Cc + o0 + r) * Ss + sqw + l15] = (pacc[r] + bo4[r]) * ym;
        }
        __builtin_amdgcn_s_setprio(0);
        asm volatile("s_waitcnt lgkmcnt(0)" ::: "memory");
        __builtin_amdgcn_s_barrier();
        if (step < 6) {
            WSTAGE(step + 2, step & 1)
            asm volatile("s_waitcnt vmcnt(4)" ::: "memory");
        } else if (step == 6) {
            asm volatile("s_waitcnt vmcnt(0)" ::: "memory");
        }
        __builtin_amdgcn_s_barrier();
    }
#undef STAGE
#undef WSTAGE
}

extern "C" void kernel_launch(void* const* d_in, const int* in_sizes, int n_in,
                              void* d_out, int out_size, void* d_ws, size_t ws_size,
                              hipStream_t stream)
{
    const float* x1   = (const float*)d_in[0];
    const float* mask = (const float*)d_in[1];
    const float* Wq   = (const float*)d_in[2];
    const float* bq   = (const float*)d_in[3];
    const float* Wk   = (const float*)d_in[4];
    const float* bk   = (const float*)d_in[5];
    const float* Wv   = (const float*)d_in[6];
    const float* bv   = (const float*)d_in[7];
    const float* Wo   = (const float*)d_in[8];
    const float* bo   = (const float*)d_in[9];
    float* y = (float*)d_out;

    // ws layout (bf16): Wqkv_b 786432 | Wo_b 262144 | qT 16777216 | kTp 17301504 | vp 17301504 |
    // xT slabs (8388608 each, 1..4 of them depending on ws_size)
    if (ws_size < 60817408u) return;
    char* w = (char*)d_ws;
    unsigned short* Wqkv_b = (unsigned short*)(w);
    unsigned short* Wo_b   = (unsigned short*)(w + 786432);
    unsigned short* qT     = (unsigned short*)(w + 1048576);
    unsigned short* kTp    = (unsigned short*)(w + 17825792);
    unsigned short* vp     = (unsigned short*)(w + 35127296);
    unsigned short* xT4    = (unsigned short*)(w + 52428800);

    int g = (int)((ws_size - 52428800u) / 8388608u);
    if (g < 1) g = 1;
    if (g > 4) g = 4;

    kprep<<<1792, 256, 0, stream>>>(Wq, Wk, Wv, Wo, Wqkv_b, Wo_b, kTp, vp);
    for (int b0 = 0; b0 < 4; b0 += g) {
        int gy = (4 - b0 < g) ? (4 - b0) : g;
        ktr_x<<<dim3(1024, gy), 256, 0, stream>>>(x1 + (long)b0 * Cc * Ss, xT4);
        kqkv<<<dim3(384, gy), 256, 0, stream>>>(xT4, Wqkv_b, bq, bk, bv, qT, kTp, vp, b0);
    }
    kattn<<<256, 512, 0, stream>>>(qT, kTp, vp, Wo_b, mask, bo, y);
}